// Round 4
// baseline (1707.213 us; speedup 1.0000x reference)
//
#include <hip/hip_runtime.h>
#include <hip/hip_bf16.h>

// Fused linear + cross-entropy forward.
//   x: [BT, H] fp32, weight: [V, H] fp32, target: [BT] int32
//   out: [0] = loss (fp32), [1..BT] = lse (fp32)
//
// Fast path:
//   K0: fp32 -> bf16 pre-pass, tiled [tile256][kt][khalf][kc4][row256][8]
//       == exactly the GEMM's LDS image (conflict-free frags, linear staging)
//   K1: 256x256 8-phase bf16 MFMA GEMM (counted vmcnt, setprio, XCD swizzle)
//       + per-tile (max, sumexp) partials
//   K2: per-row reduce -> lse, nll;  K3: mean -> loss
// Fallback path (small ws): round-2 reg-staged 128^2 kernel.

typedef __bf16 bf16x8 __attribute__((ext_vector_type(8)));
typedef float f32x16 __attribute__((ext_vector_type(16)));

#define BM 128
#define BN 128
#define BK 32
#define LDK 40      // fallback kernel LDS pad

__device__ __forceinline__ unsigned pkbf(float a, float b) {
  __hip_bfloat162 h = __float22bfloat162_rn(float2{a, b});
  unsigned r;
  __builtin_memcpy(&r, &h, 4);
  return r;
}

// global -> LDS direct copy, 16B per lane. LDS dest must be wave-uniform base.
__device__ __forceinline__ void gl16(const void* g, const void* l) {
  using GP = const unsigned __attribute__((address_space(1)))*;
  using LP = unsigned __attribute__((address_space(3)))*;
  __builtin_amdgcn_global_load_lds((GP)(unsigned long long)g,
                                   (LP)(unsigned)(unsigned long long)l, 16, 0, 0);
}

// ---- K0: convert + retile into the 256x64 K-tile image ----
// dst tile (t256, kt) at (t256*NT + kt)*16384 elems, layout [kh2][kc4][row256][8].
__global__ __launch_bounds__(256)
void k_cvt256(const float* __restrict__ src, __bf16* __restrict__ dst, int H, int NT)
{
  const int bid = blockIdx.x;
  const int kt = bid % NT;
  const int r = threadIdx.x;
  const float* s = src + (size_t)((bid / NT) * 256 + r) * H + kt * 64;
  __bf16* d = dst + (size_t)bid * 16384;
  #pragma unroll
  for (int j = 0; j < 8; ++j) {
    float4 f0 = ((const float4*)s)[2 * j];
    float4 f1 = ((const float4*)s)[2 * j + 1];
    uint4 p;
    p.x = pkbf(f0.x, f0.y); p.y = pkbf(f0.z, f0.w);
    p.z = pkbf(f1.x, f1.y); p.w = pkbf(f1.z, f1.w);
    *(uint4*)(d + (j >> 2) * 8192 + (j & 3) * 2048 + r * 8) = p;
  }
}

// ---- K1: 256^2 8-phase GEMM + per-tile (max, sumexp) partials ----
#define VM4 asm volatile("s_waitcnt vmcnt(4)" ::: "memory");
#define VM0 asm volatile("s_waitcnt vmcnt(0)" ::: "memory");
#define NOVM

// One phase: ds-load frag subtile, stage one half-tile of kt+1, barrier,
// lgkmcnt(0), prio-wrapped 8x MFMA, optional counted vmcnt, barrier.
#define PHASE(MH, KB, LOADB, STAGE_H, VMW)                                      \
  {                                                                             \
    _Pragma("unroll")                                                           \
    for (int i = 0; i < 2; ++i)                                                 \
      _Pragma("unroll")                                                         \
      for (int ks = 0; ks < 2; ++ks)                                            \
        aF[i][ks] = *(const bf16x8*)&A[(KB) * 8192 + (ks * 2 + hi) * 2048 +     \
                                       (wr * 128 + ((MH) * 2 + i) * 32 + rlo) * 8]; \
    if (LOADB) {                                                                \
      _Pragma("unroll")                                                         \
      for (int nf = 0; nf < 2; ++nf)                                            \
        _Pragma("unroll")                                                       \
        for (int ks = 0; ks < 2; ++ks)                                          \
          bF[nf][ks] = *(const bf16x8*)&B[(KB) * 8192 + (ks * 2 + hi) * 2048 +  \
                                          (wc * 64 + nf * 32 + rlo) * 8];       \
    }                                                                           \
    if (do_stage) stage_half(nbuf, kt + 1, STAGE_H);                            \
    __builtin_amdgcn_s_barrier();                                               \
    asm volatile("s_waitcnt lgkmcnt(0)" ::: "memory");                          \
    __builtin_amdgcn_sched_barrier(0);                                          \
    __builtin_amdgcn_s_setprio(1);                                              \
    _Pragma("unroll")                                                           \
    for (int i = 0; i < 2; ++i)                                                 \
      _Pragma("unroll")                                                         \
      for (int nf = 0; nf < 2; ++nf)                                            \
        _Pragma("unroll")                                                       \
        for (int ks = 0; ks < 2; ++ks)                                          \
          acc[(MH) * 2 + i][nf] = __builtin_amdgcn_mfma_f32_32x32x16_bf16(      \
              aF[i][ks], bF[nf][ks], acc[(MH) * 2 + i][nf], 0, 0, 0);           \
    __builtin_amdgcn_s_setprio(0);                                              \
    VMW                                                                         \
    __builtin_amdgcn_s_barrier();                                               \
  }

__global__ __launch_bounds__(512, 2)
void k_gemm8(const __bf16* __restrict__ xb, const __bf16* __restrict__ wb,
             const int* __restrict__ tgt,
             float* __restrict__ ws_m, float* __restrict__ ws_s,
             float* __restrict__ ws_t,
             int NT, int NCB, int ROWB)
{
  __shared__ __bf16 As[2][16384];
  __shared__ __bf16 Bs[2][16384];

  // XCD swizzle: consecutive logical tiles land on the same XCD so the 8
  // row-siblings of a column strip share that XCD's L2 for the B panel.
  int wg = blockIdx.x;
  const int nwg = gridDim.x;
  if ((nwg & 7) == 0) wg = (wg & 7) * (nwg >> 3) + (wg >> 3);
  const int rowb = wg % ROWB;
  const int cb   = wg / ROWB;
  const int row0 = rowb * 256;
  const int col0 = cb * 256;

  const int t    = threadIdx.x;
  const int lane = t & 63;
  const int wv   = t >> 6;       // 8 waves: wr = wv>>2 (2), wc = wv&3 (4)
  const int wr   = wv >> 2;
  const int wc   = wv & 3;
  const int rlo  = lane & 31;
  const int hi   = lane >> 5;

  const __bf16* ga = xb + (size_t)(rowb * NT) * 16384;
  const __bf16* gb = wb + (size_t)(cb * NT) * 16384;

  // half h: mat = h&1 (0=A,1=B), kh = h>>1. 16KB = 2 block-wide gl16 calls.
  auto stage_half = [&](int buf, int kt2, int h) {
    const int kh = h >> 1;
    const __bf16* gsrc = ((h & 1) ? gb : ga) + (size_t)kt2 * 16384 + kh * 8192;
    __bf16* lbase = ((h & 1) ? &Bs[buf][0] : &As[buf][0]) + kh * 8192;
    #pragma unroll
    for (int c = 0; c < 2; ++c)
      gl16(gsrc + c * 4096 + wv * 512 + lane * 8,
           lbase + c * 4096 + wv * 512);
  };

  // prologue: all 4 halves of kt=0; wait oldest 4 (A-k0, B-k0)
  #pragma unroll
  for (int h = 0; h < 4; ++h) stage_half(0, 0, h);
  VM4
  __builtin_amdgcn_s_barrier();

  f32x16 acc[4][2] = {};
  bf16x8 aF[2][2], bF[2][2];

  int cur = 0, kt = 0;
  const __bf16* A;
  const __bf16* B;
  bool do_stage = true;
  int nbuf;

  for (kt = 0; kt < NT - 1; ++kt) {
    A = &As[cur][0]; B = &Bs[cur][0]; nbuf = cur ^ 1;
    PHASE(0, 0, 1, 0, NOVM)
    PHASE(1, 0, 0, 1, VM4)
    PHASE(0, 1, 1, 2, NOVM)
    PHASE(1, 1, 0, 3, VM4)
    cur ^= 1;
  }
  // peeled last K-tile (no staging; drain remaining halves before k-half 1)
  A = &As[cur][0]; B = &Bs[cur][0]; nbuf = cur ^ 1; do_stage = false;
  PHASE(0, 0, 1, 0, NOVM)
  PHASE(1, 0, 0, 1, VM0)
  PHASE(0, 1, 1, 2, NOVM)
  PHASE(1, 1, 0, 3, NOVM)

  __syncthreads();  // full fence before LDS reuse for the reduction

  // Epilogue: rows span 4 waves (wc 0..3) -> two-level reduce via LDS.
  // C/D layout: col = lane&31, row = (reg&3) + 8*(reg>>2) + 4*(lane>>5)
  float* redM = (float*)&As[0][0];   // [wc4][row256]
  float* redS = redM + 1024;
  #pragma unroll
  for (int mr = 0; mr < 4; ++mr) {
    #pragma unroll
    for (int reg = 0; reg < 16; ++reg) {
      const int rl = wr * 128 + mr * 32 + (reg & 3) + 8 * (reg >> 2) + 4 * hi;
      const float v0 = acc[mr][0][reg], v1 = acc[mr][1][reg];
      float mx = fmaxf(v0, v1);
      #pragma unroll
      for (int m = 1; m < 32; m <<= 1) mx = fmaxf(mx, __shfl_xor(mx, m, 64));
      float sv = expf(v0 - mx) + expf(v1 - mx);
      #pragma unroll
      for (int m = 1; m < 32; m <<= 1) sv += __shfl_xor(sv, m, 64);
      if (rlo == 0) { redM[wc * 256 + rl] = mx; redS[wc * 256 + rl] = sv; }
      const int grow = row0 + rl;
      const int tv = tgt[grow];
      const int cbase = col0 + wc * 64;
      if (tv == cbase + rlo)      ws_t[grow] = v0;
      if (tv == cbase + 32 + rlo) ws_t[grow] = v1;
    }
  }
  __syncthreads();
  if (t < 256) {
    const float m0 = redM[t], m1 = redM[256 + t], m2 = redM[512 + t], m3 = redM[768 + t];
    float M = fmaxf(fmaxf(m0, m1), fmaxf(m2, m3));
    float S = redS[t] * expf(m0 - M) + redS[256 + t] * expf(m1 - M)
            + redS[512 + t] * expf(m2 - M) + redS[768 + t] * expf(m3 - M);
    const int grow = row0 + t;
    ws_m[(size_t)grow * NCB + cb] = M;
    ws_s[(size_t)grow * NCB + cb] = S;
  }
}

// ---- fallback: reg-staged 128^2 kernel (used if ws too small) ----
__global__ __launch_bounds__(256, 2)
void k_gemm_lse(const float* __restrict__ x, const float* __restrict__ w,
                const int* __restrict__ tgt,
                float* __restrict__ ws_m, float* __restrict__ ws_s,
                float* __restrict__ ws_t,
                int H, int NCB, int ROWB)
{
  __shared__ unsigned short As[2][BM * LDK];
  __shared__ unsigned short Bs[2][BN * LDK];

  const int bid  = blockIdx.x;
  const int rowb = bid % ROWB;
  const int cb   = bid / ROWB;
  const int row0 = rowb * BM;
  const int col0 = cb * BN;

  const int t    = threadIdx.x;
  const int lane = t & 63;
  const int wv   = t >> 6;
  const int sr = t >> 1;
  const int sk = (t & 1) * 16;

  const float* xa = x + (size_t)(row0 + sr) * H + sk;
  const float* wb = w + (size_t)(col0 + sr) * H + sk;

  float4 ra[4], rb[4];
  #pragma unroll
  for (int i = 0; i < 4; ++i) {
    ra[i] = *(const float4*)(xa + i * 4);
    rb[i] = *(const float4*)(wb + i * 4);
  }

  auto stage = [&](int buf) {
    uint4 p0, p1;
    p0.x = pkbf(ra[0].x, ra[0].y); p0.y = pkbf(ra[0].z, ra[0].w);
    p0.z = pkbf(ra[1].x, ra[1].y); p0.w = pkbf(ra[1].z, ra[1].w);
    p1.x = pkbf(ra[2].x, ra[2].y); p1.y = pkbf(ra[2].z, ra[2].w);
    p1.z = pkbf(ra[3].x, ra[3].y); p1.w = pkbf(ra[3].z, ra[3].w);
    *(uint4*)&As[buf][sr * LDK + sk]     = p0;
    *(uint4*)&As[buf][sr * LDK + sk + 8] = p1;
    p0.x = pkbf(rb[0].x, rb[0].y); p0.y = pkbf(rb[0].z, rb[0].w);
    p0.z = pkbf(rb[1].x, rb[1].y); p0.w = pkbf(rb[1].z, rb[1].w);
    p1.x = pkbf(rb[2].x, rb[2].y); p1.y = pkbf(rb[2].z, rb[2].w);
    p1.z = pkbf(rb[3].x, rb[3].y); p1.w = pkbf(rb[3].z, rb[3].w);
    *(uint4*)&Bs[buf][sr * LDK + sk]     = p0;
    *(uint4*)&Bs[buf][sr * LDK + sk + 8] = p1;
  };

  stage(0);
  __syncthreads();

  f32x16 acc[4] = {};
  const int rlo = lane & 31;
  const int hi  = lane >> 5;
  const int NT  = H / BK;
  int cur = 0;

  for (int kt = 0; kt < NT; ++kt) {
    const bool pf = (kt + 1 < NT);
    if (pf) {
      xa += BK; wb += BK;
      #pragma unroll
      for (int i = 0; i < 4; ++i) {
        ra[i] = *(const float4*)(xa + i * 4);
        rb[i] = *(const float4*)(wb + i * 4);
      }
    }
    const unsigned short* A = As[cur];
    const unsigned short* B = Bs[cur];
    #pragma unroll
    for (int ks = 0; ks < 2; ++ks) {
      const int koff = ks * 16 + hi * 8;
      bf16x8 a = *(const bf16x8*)&A[(wv * 32 + rlo) * LDK + koff];
      #pragma unroll
      for (int nf = 0; nf < 4; ++nf) {
        bf16x8 b = *(const bf16x8*)&B[(nf * 32 + rlo) * LDK + koff];
        acc[nf] = __builtin_amdgcn_mfma_f32_32x32x16_bf16(a, b, acc[nf], 0, 0, 0);
      }
    }
    if (pf) stage(cur ^ 1);
    __syncthreads();
    cur ^= 1;
  }

  #pragma unroll
  for (int reg = 0; reg < 16; ++reg) {
    const int row = wv * 32 + (reg & 3) + 8 * (reg >> 2) + 4 * hi;
    float mx = fmaxf(fmaxf(acc[0][reg], acc[1][reg]), fmaxf(acc[2][reg], acc[3][reg]));
    #pragma unroll
    for (int m = 1; m < 32; m <<= 1) mx = fmaxf(mx, __shfl_xor(mx, m, 64));
    float s = 0.f;
    #pragma unroll
    for (int nf = 0; nf < 4; ++nf) s += expf(acc[nf][reg] - mx);
    #pragma unroll
    for (int m = 1; m < 32; m <<= 1) s += __shfl_xor(s, m, 64);
    const int grow = row0 + row;
    if (rlo == 0) {
      ws_m[(size_t)grow * NCB + cb] = mx;
      ws_s[(size_t)grow * NCB + cb] = s;
    }
    const int tv = tgt[grow];
    #pragma unroll
    for (int nf = 0; nf < 4; ++nf) {
      if (tv == col0 + nf * 32 + rlo) ws_t[grow] = acc[nf][reg];
    }
  }
}

__global__ void k_rowlse(const float* __restrict__ ws_m, const float* __restrict__ ws_s,
                         const float* __restrict__ ws_t, const int* __restrict__ tgt,
                         float* __restrict__ out, float* __restrict__ ws_nll, int NCB)
{
  const int row = blockIdx.x;
  const int t = threadIdx.x;
  const float* pm = ws_m + (size_t)row * NCB;
  const float* ps = ws_s + (size_t)row * NCB;
  __shared__ float red[8];

  float M = -3.0e38f;
  for (int j = t; j < NCB; j += 256) M = fmaxf(M, pm[j]);
  #pragma unroll
  for (int m = 1; m < 64; m <<= 1) M = fmaxf(M, __shfl_xor(M, m, 64));
  if ((t & 63) == 0) red[t >> 6] = M;
  __syncthreads();
  M = fmaxf(fmaxf(red[0], red[1]), fmaxf(red[2], red[3]));

  float S = 0.f;
  for (int j = t; j < NCB; j += 256) S += ps[j] * expf(pm[j] - M);
  #pragma unroll
  for (int m = 1; m < 64; m <<= 1) S += __shfl_xor(S, m, 64);
  if ((t & 63) == 0) red[4 + (t >> 6)] = S;
  __syncthreads();

  if (t == 0) {
    S = red[4] + red[5] + red[6] + red[7];
    const float lse = M + logf(S);
    out[1 + row] = lse;
    const int tv = tgt[row];
    ws_nll[row] = (tv != -100) ? (lse - ws_t[row]) : 0.f;
  }
}

__global__ void k_loss(const float* __restrict__ ws_nll, const int* __restrict__ tgt,
                       float* __restrict__ out, int BT)
{
  const int t = threadIdx.x;
  float s = 0.f, c = 0.f;
  for (int i = t; i < BT; i += 256) {
    s += ws_nll[i];
    c += (tgt[i] != -100) ? 1.f : 0.f;
  }
  __shared__ float rs[4], rc[4];
  #pragma unroll
  for (int m = 1; m < 64; m <<= 1) { s += __shfl_xor(s, m, 64); c += __shfl_xor(c, m, 64); }
  if ((t & 63) == 0) { rs[t >> 6] = s; rc[t >> 6] = c; }
  __syncthreads();
  if (t == 0) {
    s = rs[0] + rs[1] + rs[2] + rs[3];
    c = rc[0] + rc[1] + rc[2] + rc[3];
    out[0] = s / c;
  }
}

extern "C" void kernel_launch(void* const* d_in, const int* in_sizes, int n_in,
                              void* d_out, int out_size, void* d_ws, size_t ws_size,
                              hipStream_t stream)
{
  const float* x  = (const float*)d_in[0];
  const float* w  = (const float*)d_in[1];
  const int* tgt  = (const int*)d_in[2];
  float* out      = (float*)d_out;

  const int BT = in_sizes[2];
  const int H  = in_sizes[0] / BT;          // 2048
  const int V  = in_sizes[1] / H;           // 128000

  const int NT    = H / 64;                 // 32
  const int ROWB  = BT / 256;               // 8
  const int NCB   = V / 256;                // 500

  const size_t bf_elems   = (size_t)BT * H + (size_t)V * H;
  const size_t need_bytes = bf_elems * 2 + ((size_t)2 * BT * NCB + 2 * (size_t)BT) * 4;

  if (ws_size >= need_bytes && (BT % 256) == 0 && (V % 256) == 0 && (H % 64) == 0) {
    // ws = x_bf | w_bf | m | s | tgt_logit | nll
    __bf16* x_bf = (__bf16*)d_ws;
    __bf16* w_bf = x_bf + (size_t)BT * H;
    float* ws_m   = (float*)(w_bf + (size_t)V * H);
    float* ws_s   = ws_m + (size_t)BT * NCB;
    float* ws_t   = ws_s + (size_t)BT * NCB;
    float* ws_nll = ws_t + BT;

    k_cvt256<<<(V / 256) * NT, 256, 0, stream>>>(w, w_bf, H, NT);
    k_cvt256<<<(BT / 256) * NT, 256, 0, stream>>>(x, x_bf, H, NT);
    k_gemm8<<<ROWB * NCB, 512, 0, stream>>>(x_bf, w_bf, tgt, ws_m, ws_s, ws_t, NT, NCB, ROWB);
    k_rowlse<<<BT, 256, 0, stream>>>(ws_m, ws_s, ws_t, tgt, out, ws_nll, NCB);
    k_loss<<<1, 256, 0, stream>>>(ws_nll, tgt, out, BT);
  } else {
    const int ROWB1 = BT / BM;              // 16
    const int NCB1  = V / BN;               // 1000
    float* ws_m   = (float*)d_ws;
    float* ws_s   = ws_m + (size_t)BT * NCB1;
    float* ws_t   = ws_s + (size_t)BT * NCB1;
    float* ws_nll = ws_t + BT;

    k_gemm_lse<<<ROWB1 * NCB1, 256, 0, stream>>>(x, w, tgt, ws_m, ws_s, ws_t, H, NCB1, ROWB1);
    k_rowlse<<<BT, 256, 0, stream>>>(ws_m, ws_s, ws_t, tgt, out, ws_nll, NCB1);
    k_loss<<<1, 256, 0, stream>>>(ws_nll, tgt, out, BT);
  }
}

// Round 5
// 1623.525 us; speedup vs baseline: 1.0515x; 1.0515x over previous
//
#include <hip/hip_runtime.h>
#include <hip/hip_bf16.h>

// Fused linear + cross-entropy forward.
//   x: [BT, H] fp32, weight: [V, H] fp32, target: [BT] int32
//   out: [0] = loss (fp32), [1..BT] = lse (fp32)
//
// Fast path:
//   K0: fp32 -> bf16 pre-pass, tiled [tile256][kt][kh2][kc4][row256][8]
//       == exactly the GEMM's LDS image (conflict-free frags, linear staging)
//   Kt: exact fp32 target-logit dot (one wave per row)
//   K1: 256x256 bf16 MFMA GEMM, 2 phases/K-tile x 16 MFMA, counted vmcnt(4),
//       setprio, XCD swizzle; compiler-managed lgkmcnt (no forced drains)
//   K2: per-row reduce -> lse, nll;  K3: mean -> loss
// Fallback path (small ws): reg-staged 128^2 kernel.

typedef __bf16 bf16x8 __attribute__((ext_vector_type(8)));
typedef float f32x16 __attribute__((ext_vector_type(16)));

#define BM 128
#define BN 128
#define BK 32
#define LDK 40      // fallback kernel LDS pad

__device__ __forceinline__ unsigned pkbf(float a, float b) {
  __hip_bfloat162 h = __float22bfloat162_rn(float2{a, b});
  unsigned r;
  __builtin_memcpy(&r, &h, 4);
  return r;
}

// global -> LDS direct copy, 16B per lane. LDS dest must be wave-uniform base.
__device__ __forceinline__ void gl16(const void* g, const void* l) {
  using GP = const unsigned __attribute__((address_space(1)))*;
  using LP = unsigned __attribute__((address_space(3)))*;
  __builtin_amdgcn_global_load_lds((GP)(unsigned long long)g,
                                   (LP)(unsigned)(unsigned long long)l, 16, 0, 0);
}

// ---- K0: convert + retile into the 256x64 K-tile image ----
// dst tile (t256, kt) at (t256*NT + kt)*16384 elems, layout [kh2][kc4][row256][8].
__global__ __launch_bounds__(256)
void k_cvt256(const float* __restrict__ src, __bf16* __restrict__ dst, int H, int NT)
{
  const int bid = blockIdx.x;
  const int kt = bid % NT;
  const int r = threadIdx.x;
  const float* s = src + (size_t)((bid / NT) * 256 + r) * H + kt * 64;
  __bf16* d = dst + (size_t)bid * 16384;
  #pragma unroll
  for (int j = 0; j < 8; ++j) {
    float4 f0 = ((const float4*)s)[2 * j];
    float4 f1 = ((const float4*)s)[2 * j + 1];
    uint4 p;
    p.x = pkbf(f0.x, f0.y); p.y = pkbf(f0.z, f0.w);
    p.z = pkbf(f1.x, f1.y); p.w = pkbf(f1.z, f1.w);
    *(uint4*)(d + (j >> 2) * 8192 + (j & 3) * 2048 + r * 8) = p;
  }
}

// ---- Kt: exact fp32 target logit, one wave per row ----
__global__ __launch_bounds__(256)
void k_tgt(const float* __restrict__ x, const float* __restrict__ w,
           const int* __restrict__ tgt, float* __restrict__ ws_t, int H)
{
  const int row  = blockIdx.x * 4 + (threadIdx.x >> 6);
  const int lane = threadIdx.x & 63;
  const int tv = tgt[row];
  if (tv == -100) { if (lane == 0) ws_t[row] = 0.f; return; }
  const float* xr = x + (size_t)row * H;
  const float* wr = w + (size_t)tv * H;
  float acc = 0.f;
  for (int j = lane * 4; j < H; j += 256) {
    float4 a = *(const float4*)(xr + j);
    float4 b = *(const float4*)(wr + j);
    acc += a.x * b.x + a.y * b.y + a.z * b.z + a.w * b.w;
  }
  #pragma unroll
  for (int m = 1; m < 64; m <<= 1) acc += __shfl_xor(acc, m, 64);
  if (lane == 0) ws_t[row] = acc;
}

// ---- K1: 256^2 GEMM, 2 phases/K-tile, + per-tile (max, sumexp) partials ----
#define VM4 asm volatile("s_waitcnt vmcnt(4)" ::: "memory");
#define VM0 asm volatile("s_waitcnt vmcnt(0)" ::: "memory");
#define NOVM

// One phase (k-half KB): 12 ds_read_b128, stage 2 half-tiles of kt+1,
// barrier, prio-wrapped 16x MFMA (compiler inserts fine lgkmcnt), counted
// vmcnt, barrier.
#define PHASE(KB, VMW)                                                          \
  {                                                                             \
    _Pragma("unroll")                                                           \
    for (int i = 0; i < 4; ++i)                                                 \
      _Pragma("unroll")                                                         \
      for (int ks = 0; ks < 2; ++ks)                                            \
        aF[i][ks] = *(const bf16x8*)&A[(KB) * 8192 + (ks * 2 + hi) * 2048 +     \
                                       (wr * 128 + i * 32 + rlo) * 8];          \
    _Pragma("unroll")                                                           \
    for (int nf = 0; nf < 2; ++nf)                                              \
      _Pragma("unroll")                                                         \
      for (int ks = 0; ks < 2; ++ks)                                            \
        bF[nf][ks] = *(const bf16x8*)&B[(KB) * 8192 + (ks * 2 + hi) * 2048 +    \
                                        (wc * 64 + nf * 32 + rlo) * 8];         \
    if (do_stage) {                                                             \
      stage_half(nbuf, kt + 1, (KB) * 2);                                       \
      stage_half(nbuf, kt + 1, (KB) * 2 + 1);                                   \
    }                                                                           \
    __builtin_amdgcn_s_barrier();                                               \
    __builtin_amdgcn_s_setprio(1);                                              \
    _Pragma("unroll")                                                           \
    for (int i = 0; i < 4; ++i)                                                 \
      _Pragma("unroll")                                                         \
      for (int nf = 0; nf < 2; ++nf)                                            \
        _Pragma("unroll")                                                       \
        for (int ks = 0; ks < 2; ++ks)                                          \
          acc[i][nf] = __builtin_amdgcn_mfma_f32_32x32x16_bf16(                 \
              aF[i][ks], bF[nf][ks], acc[i][nf], 0, 0, 0);                      \
    __builtin_amdgcn_s_setprio(0);                                              \
    VMW                                                                         \
    __builtin_amdgcn_s_barrier();                                               \
  }

__global__ __launch_bounds__(512, 2)
void k_gemm8(const __bf16* __restrict__ xb, const __bf16* __restrict__ wb,
             float* __restrict__ ws_m, float* __restrict__ ws_s,
             int NT, int NCB, int ROWB)
{
  __shared__ __bf16 As[2][16384];
  __shared__ __bf16 Bs[2][16384];

  // XCD swizzle: the 8 row-siblings of a column strip land on one XCD ->
  // B panel (1MB) served from that XCD's L2.
  int wg = blockIdx.x;
  const int nwg = gridDim.x;
  if ((nwg & 7) == 0) wg = (wg & 7) * (nwg >> 3) + (wg >> 3);
  const int rowb = wg % ROWB;
  const int cb   = wg / ROWB;
  const int row0 = rowb * 256;

  const int t    = threadIdx.x;
  const int lane = t & 63;
  const int wv   = t >> 6;       // 8 waves: wr = wv>>2 (2), wc = wv&3 (4)
  const int wr   = wv >> 2;
  const int wc   = wv & 3;
  const int rlo  = lane & 31;
  const int hi   = lane >> 5;

  const __bf16* ga = xb + (size_t)(rowb * NT) * 16384;
  const __bf16* gb = wb + (size_t)(cb * NT) * 16384;

  // half h: mat = h&1 (0=A,1=B), kh = h>>1. 16KB = 2 block-wide gl16 sweeps.
  auto stage_half = [&](int buf, int kt2, int h) {
    const int kh = h >> 1;
    const __bf16* gsrc = ((h & 1) ? gb : ga) + (size_t)kt2 * 16384 + kh * 8192;
    __bf16* lbase = ((h & 1) ? &Bs[buf][0] : &As[buf][0]) + kh * 8192;
    #pragma unroll
    for (int c = 0; c < 2; ++c)
      gl16(gsrc + c * 4096 + wv * 512 + lane * 8,
           lbase + c * 4096 + wv * 512);
  };

  // prologue: all 4 halves of kt=0; wait oldest 4 (A-kh0, B-kh0).
  // Steady-state invariant at phase-A entry: kh0 of current tile complete,
  // kh1 outstanding (4 loads).
  #pragma unroll
  for (int h = 0; h < 4; ++h) stage_half(0, 0, h);
  VM4
  __builtin_amdgcn_s_barrier();

  f32x16 acc[4][2] = {};
  bf16x8 aF[4][2], bF[2][2];

  int cur = 0, kt = 0;
  const __bf16* A;
  const __bf16* B;
  bool do_stage = true;
  int nbuf;

  for (kt = 0; kt < NT - 1; ++kt) {
    A = &As[cur][0]; B = &Bs[cur][0]; nbuf = cur ^ 1;
    // phase A: VM4 waits kh1(kt) [oldest 4 of 8]; phase B: VM4 waits kh0(kt+1).
    PHASE(0, VM4)
    PHASE(1, VM4)
    cur ^= 1;
  }
  // peeled last K-tile: entry outstanding = kh1(kt_last) only -> VM0 drains it.
  A = &As[cur][0]; B = &Bs[cur][0]; nbuf = cur ^ 1; do_stage = false;
  PHASE(0, VM0)
  PHASE(1, NOVM)

  __syncthreads();  // full fence before LDS reuse for the reduction

  // Epilogue: rows span 4 waves (wc 0..3) -> two-level reduce via LDS.
  // C/D layout: col = lane&31, row = (reg&3) + 8*(reg>>2) + 4*(lane>>5)
  float* redM = (float*)&As[0][0];   // [wc4][row256]
  float* redS = redM + 1024;
  #pragma unroll
  for (int mr = 0; mr < 4; ++mr) {
    #pragma unroll
    for (int reg = 0; reg < 16; ++reg) {
      const int rl = wr * 128 + mr * 32 + (reg & 3) + 8 * (reg >> 2) + 4 * hi;
      const float v0 = acc[mr][0][reg], v1 = acc[mr][1][reg];
      float mx = fmaxf(v0, v1);
      #pragma unroll
      for (int m = 1; m < 32; m <<= 1) mx = fmaxf(mx, __shfl_xor(mx, m, 64));
      float sv = expf(v0 - mx) + expf(v1 - mx);
      #pragma unroll
      for (int m = 1; m < 32; m <<= 1) sv += __shfl_xor(sv, m, 64);
      if (rlo == 0) { redM[wc * 256 + rl] = mx; redS[wc * 256 + rl] = sv; }
    }
  }
  __syncthreads();
  if (t < 256) {
    const float m0 = redM[t], m1 = redM[256 + t], m2 = redM[512 + t], m3 = redM[768 + t];
    float M = fmaxf(fmaxf(m0, m1), fmaxf(m2, m3));
    float S = redS[t] * expf(m0 - M) + redS[256 + t] * expf(m1 - M)
            + redS[512 + t] * expf(m2 - M) + redS[768 + t] * expf(m3 - M);
    const int grow = row0 + t;
    ws_m[(size_t)grow * NCB + cb] = M;
    ws_s[(size_t)grow * NCB + cb] = S;
  }
}

// ---- fallback: reg-staged 128^2 kernel (used if ws too small) ----
__global__ __launch_bounds__(256, 2)
void k_gemm_lse(const float* __restrict__ x, const float* __restrict__ w,
                const int* __restrict__ tgt,
                float* __restrict__ ws_m, float* __restrict__ ws_s,
                float* __restrict__ ws_t,
                int H, int NCB, int ROWB)
{
  __shared__ unsigned short As[2][BM * LDK];
  __shared__ unsigned short Bs[2][BN * LDK];

  const int bid  = blockIdx.x;
  const int rowb = bid % ROWB;
  const int cb   = bid / ROWB;
  const int row0 = rowb * BM;
  const int col0 = cb * BN;

  const int t    = threadIdx.x;
  const int lane = t & 63;
  const int wv   = t >> 6;
  const int sr = t >> 1;
  const int sk = (t & 1) * 16;

  const float* xa = x + (size_t)(row0 + sr) * H + sk;
  const float* wb = w + (size_t)(col0 + sr) * H + sk;

  float4 ra[4], rb[4];
  #pragma unroll
  for (int i = 0; i < 4; ++i) {
    ra[i] = *(const float4*)(xa + i * 4);
    rb[i] = *(const float4*)(wb + i * 4);
  }

  auto stage = [&](int buf) {
    uint4 p0, p1;
    p0.x = pkbf(ra[0].x, ra[0].y); p0.y = pkbf(ra[0].z, ra[0].w);
    p0.z = pkbf(ra[1].x, ra[1].y); p0.w = pkbf(ra[1].z, ra[1].w);
    p1.x = pkbf(ra[2].x, ra[2].y); p1.y = pkbf(ra[2].z, ra[2].w);
    p1.z = pkbf(ra[3].x, ra[3].y); p1.w = pkbf(ra[3].z, ra[3].w);
    *(uint4*)&As[buf][sr * LDK + sk]     = p0;
    *(uint4*)&As[buf][sr * LDK + sk + 8] = p1;
    p0.x = pkbf(rb[0].x, rb[0].y); p0.y = pkbf(rb[0].z, rb[0].w);
    p0.z = pkbf(rb[1].x, rb[1].y); p0.w = pkbf(rb[1].z, rb[1].w);
    p1.x = pkbf(rb[2].x, rb[2].y); p1.y = pkbf(rb[2].z, rb[2].w);
    p1.z = pkbf(rb[3].x, rb[3].y); p1.w = pkbf(rb[3].z, rb[3].w);
    *(uint4*)&Bs[buf][sr * LDK + sk]     = p0;
    *(uint4*)&Bs[buf][sr * LDK + sk + 8] = p1;
  };

  stage(0);
  __syncthreads();

  f32x16 acc[4] = {};
  const int rlo = lane & 31;
  const int hi  = lane >> 5;
  const int NT  = H / BK;
  int cur = 0;

  for (int kt = 0; kt < NT; ++kt) {
    const bool pf = (kt + 1 < NT);
    if (pf) {
      xa += BK; wb += BK;
      #pragma unroll
      for (int i = 0; i < 4; ++i) {
        ra[i] = *(const float4*)(xa + i * 4);
        rb[i] = *(const float4*)(wb + i * 4);
      }
    }
    const unsigned short* A = As[cur];
    const unsigned short* B = Bs[cur];
    #pragma unroll
    for (int ks = 0; ks < 2; ++ks) {
      const int koff = ks * 16 + hi * 8;
      bf16x8 a = *(const bf16x8*)&A[(wv * 32 + rlo) * LDK + koff];
      #pragma unroll
      for (int nf = 0; nf < 4; ++nf) {
        bf16x8 b = *(const bf16x8*)&B[(nf * 32 + rlo) * LDK + koff];
        acc[nf] = __builtin_amdgcn_mfma_f32_32x32x16_bf16(a, b, acc[nf], 0, 0, 0);
      }
    }
    if (pf) stage(cur ^ 1);
    __syncthreads();
    cur ^= 1;
  }

  #pragma unroll
  for (int reg = 0; reg < 16; ++reg) {
    const int row = wv * 32 + (reg & 3) + 8 * (reg >> 2) + 4 * hi;
    float mx = fmaxf(fmaxf(acc[0][reg], acc[1][reg]), fmaxf(acc[2][reg], acc[3][reg]));
    #pragma unroll
    for (int m = 1; m < 32; m <<= 1) mx = fmaxf(mx, __shfl_xor(mx, m, 64));
    float s = 0.f;
    #pragma unroll
    for (int nf = 0; nf < 4; ++nf) s += expf(acc[nf][reg] - mx);
    #pragma unroll
    for (int m = 1; m < 32; m <<= 1) s += __shfl_xor(s, m, 64);
    const int grow = row0 + row;
    if (rlo == 0) {
      ws_m[(size_t)grow * NCB + cb] = mx;
      ws_s[(size_t)grow * NCB + cb] = s;
    }
    const int tv = tgt[grow];
    #pragma unroll
    for (int nf = 0; nf < 4; ++nf) {
      if (tv == col0 + nf * 32 + rlo) ws_t[grow] = acc[nf][reg];
    }
  }
}

__global__ void k_rowlse(const float* __restrict__ ws_m, const float* __restrict__ ws_s,
                         const float* __restrict__ ws_t, const int* __restrict__ tgt,
                         float* __restrict__ out, float* __restrict__ ws_nll, int NCB)
{
  const int row = blockIdx.x;
  const int t = threadIdx.x;
  const float* pm = ws_m + (size_t)row * NCB;
  const float* ps = ws_s + (size_t)row * NCB;
  __shared__ float red[8];

  float M = -3.0e38f;
  for (int j = t; j < NCB; j += 256) M = fmaxf(M, pm[j]);
  #pragma unroll
  for (int m = 1; m < 64; m <<= 1) M = fmaxf(M, __shfl_xor(M, m, 64));
  if ((t & 63) == 0) red[t >> 6] = M;
  __syncthreads();
  M = fmaxf(fmaxf(red[0], red[1]), fmaxf(red[2], red[3]));

  float S = 0.f;
  for (int j = t; j < NCB; j += 256) S += ps[j] * expf(pm[j] - M);
  #pragma unroll
  for (int m = 1; m < 64; m <<= 1) S += __shfl_xor(S, m, 64);
  if ((t & 63) == 0) red[4 + (t >> 6)] = S;
  __syncthreads();

  if (t == 0) {
    S = red[4] + red[5] + red[6] + red[7];
    const float lse = M + logf(S);
    out[1 + row] = lse;
    const int tv = tgt[row];
    ws_nll[row] = (tv != -100) ? (lse - ws_t[row]) : 0.f;
  }
}

__global__ void k_loss(const float* __restrict__ ws_nll, const int* __restrict__ tgt,
                       float* __restrict__ out, int BT)
{
  const int t = threadIdx.x;
  float s = 0.f, c = 0.f;
  for (int i = t; i < BT; i += 256) {
    s += ws_nll[i];
    c += (tgt[i] != -100) ? 1.f : 0.f;
  }
  __shared__ float rs[4], rc[4];
  #pragma unroll
  for (int m = 1; m < 64; m <<= 1) { s += __shfl_xor(s, m, 64); c += __shfl_xor(c, m, 64); }
  if ((t & 63) == 0) { rs[t >> 6] = s; rc[t >> 6] = c; }
  __syncthreads();
  if (t == 0) {
    s = rs[0] + rs[1] + rs[2] + rs[3];
    c = rc[0] + rc[1] + rc[2] + rc[3];
    out[0] = s / c;
  }
}

extern "C" void kernel_launch(void* const* d_in, const int* in_sizes, int n_in,
                              void* d_out, int out_size, void* d_ws, size_t ws_size,
                              hipStream_t stream)
{
  const float* x  = (const float*)d_in[0];
  const float* w  = (const float*)d_in[1];
  const int* tgt  = (const int*)d_in[2];
  float* out      = (float*)d_out;

  const int BT = in_sizes[2];
  const int H  = in_sizes[0] / BT;          // 2048
  const int V  = in_sizes[1] / H;           // 128000

  const int NT    = H / 64;                 // 32
  const int ROWB  = BT / 256;               // 8
  const int NCB   = V / 256;                // 500

  const size_t bf_elems   = (size_t)BT * H + (size_t)V * H;
  const size_t need_bytes = bf_elems * 2 + ((size_t)2 * BT * NCB + 2 * (size_t)BT) * 4;

  if (ws_size >= need_bytes && (BT % 256) == 0 && (V % 256) == 0 && (H % 64) == 0) {
    // ws = x_bf | w_bf | m | s | tgt_logit | nll
    __bf16* x_bf = (__bf16*)d_ws;
    __bf16* w_bf = x_bf + (size_t)BT * H;
    float* ws_m   = (float*)(w_bf + (size_t)V * H);
    float* ws_s   = ws_m + (size_t)BT * NCB;
    float* ws_t   = ws_s + (size_t)BT * NCB;
    float* ws_nll = ws_t + BT;

    k_cvt256<<<(V / 256) * NT, 256, 0, stream>>>(w, w_bf, H, NT);
    k_cvt256<<<(BT / 256) * NT, 256, 0, stream>>>(x, x_bf, H, NT);
    k_tgt<<<BT / 4, 256, 0, stream>>>(x, w, tgt, ws_t, H);
    k_gemm8<<<ROWB * NCB, 512, 0, stream>>>(x_bf, w_bf, ws_m, ws_s, NT, NCB, ROWB);
    k_rowlse<<<BT, 256, 0, stream>>>(ws_m, ws_s, ws_t, tgt, out, ws_nll, NCB);
    k_loss<<<1, 256, 0, stream>>>(ws_nll, tgt, out, BT);
  } else {
    const int ROWB1 = BT / BM;              // 16
    const int NCB1  = V / BN;               // 1000
    float* ws_m   = (float*)d_ws;
    float* ws_s   = ws_m + (size_t)BT * NCB1;
    float* ws_t   = ws_s + (size_t)BT * NCB1;
    float* ws_nll = ws_t + BT;

    k_gemm_lse<<<ROWB1 * NCB1, 256, 0, stream>>>(x, w, tgt, ws_m, ws_s, ws_t, H, NCB1, ROWB1);
    k_rowlse<<<BT, 256, 0, stream>>>(ws_m, ws_s, ws_t, tgt, out, ws_nll, NCB1);
    k_loss<<<1, 256, 0, stream>>>(ws_nll, tgt, out, BT);
  }
}

// Round 6
// 1616.401 us; speedup vs baseline: 1.0562x; 1.0044x over previous
//
#include <hip/hip_runtime.h>
#include <hip/hip_bf16.h>

// Fused linear + cross-entropy forward.
//   x: [BT, H] fp32, weight: [V, H] fp32, target: [BT] int32
//   out: [0] = loss (fp32), [1..BT] = lse (fp32)
//
// Fast path:
//   K0: fp32 -> bf16 pre-pass, tiled [tile256][kt][kh2][kc4][row256][8]
//       == exactly the GEMM's LDS image (conflict-free frags, linear staging)
//   Kt: exact fp32 target-logit dot (one wave per row)
//   K1: 256x256 bf16 MFMA GEMM, 4 sub-phases/K-tile x 8 MFMA, dual barrier,
//       lgkmcnt(0) (NO sched_barrier - m141 poison), setprio, counted vmcnt(4),
//       XCD swizzle
//   K2: per-row reduce -> lse, nll;  K3: mean -> loss
// Fallback path (small ws): reg-staged 128^2 kernel.

typedef __bf16 bf16x8 __attribute__((ext_vector_type(8)));
typedef float f32x16 __attribute__((ext_vector_type(16)));

#define BM 128
#define BN 128
#define BK 32
#define LDK 40      // fallback kernel LDS pad

__device__ __forceinline__ unsigned pkbf(float a, float b) {
  __hip_bfloat162 h = __float22bfloat162_rn(float2{a, b});
  unsigned r;
  __builtin_memcpy(&r, &h, 4);
  return r;
}

// global -> LDS direct copy, 16B per lane. LDS dest must be wave-uniform base.
__device__ __forceinline__ void gl16(const void* g, const void* l) {
  using GP = const unsigned __attribute__((address_space(1)))*;
  using LP = unsigned __attribute__((address_space(3)))*;
  __builtin_amdgcn_global_load_lds((GP)(unsigned long long)g,
                                   (LP)(unsigned)(unsigned long long)l, 16, 0, 0);
}

// ---- K0: convert + retile into the 256x64 K-tile image ----
// dst tile (t256, kt) at (t256*NT + kt)*16384 elems, layout [kh2][kc4][row256][8].
__global__ __launch_bounds__(256)
void k_cvt256(const float* __restrict__ src, __bf16* __restrict__ dst, int H, int NT)
{
  const int bid = blockIdx.x;
  const int kt = bid % NT;
  const int r = threadIdx.x;
  const float* s = src + (size_t)((bid / NT) * 256 + r) * H + kt * 64;
  __bf16* d = dst + (size_t)bid * 16384;
  #pragma unroll
  for (int j = 0; j < 8; ++j) {
    float4 f0 = ((const float4*)s)[2 * j];
    float4 f1 = ((const float4*)s)[2 * j + 1];
    uint4 p;
    p.x = pkbf(f0.x, f0.y); p.y = pkbf(f0.z, f0.w);
    p.z = pkbf(f1.x, f1.y); p.w = pkbf(f1.z, f1.w);
    *(uint4*)(d + (j >> 2) * 8192 + (j & 3) * 2048 + r * 8) = p;
  }
}

// ---- Kt: exact fp32 target logit, one wave per row ----
__global__ __launch_bounds__(256)
void k_tgt(const float* __restrict__ x, const float* __restrict__ w,
           const int* __restrict__ tgt, float* __restrict__ ws_t, int H)
{
  const int row  = blockIdx.x * 4 + (threadIdx.x >> 6);
  const int lane = threadIdx.x & 63;
  const int tv = tgt[row];
  if (tv == -100) { if (lane == 0) ws_t[row] = 0.f; return; }
  const float* xr = x + (size_t)row * H;
  const float* wr = w + (size_t)tv * H;
  float acc = 0.f;
  for (int j = lane * 4; j < H; j += 256) {
    float4 a = *(const float4*)(xr + j);
    float4 b = *(const float4*)(wr + j);
    acc += a.x * b.x + a.y * b.y + a.z * b.z + a.w * b.w;
  }
  #pragma unroll
  for (int m = 1; m < 64; m <<= 1) acc += __shfl_xor(acc, m, 64);
  if (lane == 0) ws_t[row] = acc;
}

// ---- K1: 256^2 GEMM, 4 sub-phases/K-tile + per-tile (max, sumexp) partials ----
#define VM4 asm volatile("s_waitcnt vmcnt(4)" ::: "memory");
#define VM0 asm volatile("s_waitcnt vmcnt(0)" ::: "memory");
#define NOVM

// One sub-phase: ds-load A-half (4 b128) [+ B (4 b128) on MH0], stage one
// half-tile of kt+1, barrier, lgkmcnt(0), prio-wrapped 8x MFMA, counted
// vmcnt, barrier.  NO sched_barrier (m141: order-pinning regression).
#define PHASE(MH, KB, LOADB, STAGE_H, VMW)                                      \
  {                                                                             \
    _Pragma("unroll")                                                           \
    for (int i = 0; i < 2; ++i)                                                 \
      _Pragma("unroll")                                                         \
      for (int ks = 0; ks < 2; ++ks)                                            \
        aF[i][ks] = *(const bf16x8*)&A[(KB) * 8192 + (ks * 2 + hi) * 2048 +     \
                                       (wr * 128 + ((MH) * 2 + i) * 32 + rlo) * 8]; \
    if (LOADB) {                                                                \
      _Pragma("unroll")                                                         \
      for (int nf = 0; nf < 2; ++nf)                                            \
        _Pragma("unroll")                                                       \
        for (int ks = 0; ks < 2; ++ks)                                          \
          bF[nf][ks] = *(const bf16x8*)&B[(KB) * 8192 + (ks * 2 + hi) * 2048 +  \
                                          (wc * 64 + nf * 32 + rlo) * 8];       \
    }                                                                           \
    if (do_stage) stage_half(nbuf, kt + 1, STAGE_H);                            \
    __builtin_amdgcn_s_barrier();                                               \
    asm volatile("s_waitcnt lgkmcnt(0)" ::: "memory");                          \
    __builtin_amdgcn_s_setprio(1);                                              \
    _Pragma("unroll")                                                           \
    for (int i = 0; i < 2; ++i)                                                 \
      _Pragma("unroll")                                                         \
      for (int nf = 0; nf < 2; ++nf)                                            \
        _Pragma("unroll")                                                       \
        for (int ks = 0; ks < 2; ++ks)                                          \
          acc[(MH) * 2 + i][nf] = __builtin_amdgcn_mfma_f32_32x32x16_bf16(      \
              aF[i][ks], bF[nf][ks], acc[(MH) * 2 + i][nf], 0, 0, 0);           \
    __builtin_amdgcn_s_setprio(0);                                              \
    VMW                                                                         \
    __builtin_amdgcn_s_barrier();                                               \
  }

__global__ __launch_bounds__(512, 2)
void k_gemm8(const __bf16* __restrict__ xb, const __bf16* __restrict__ wb,
             float* __restrict__ ws_m, float* __restrict__ ws_s,
             int NT, int NCB, int ROWB)
{
  __shared__ __bf16 As[2][16384];
  __shared__ __bf16 Bs[2][16384];

  // XCD swizzle: the 8 row-siblings of a column strip land on one XCD ->
  // B panel (1MB) served from that XCD's L2.
  int wg = blockIdx.x;
  const int nwg = gridDim.x;
  if ((nwg & 7) == 0) wg = (wg & 7) * (nwg >> 3) + (wg >> 3);
  const int rowb = wg % ROWB;
  const int cb   = wg / ROWB;
  const int row0 = rowb * 256;

  const int t    = threadIdx.x;
  const int lane = t & 63;
  const int wv   = t >> 6;       // 8 waves: wr = wv>>2 (2), wc = wv&3 (4)
  const int wr   = wv >> 2;
  const int wc   = wv & 3;
  const int rlo  = lane & 31;
  const int hi   = lane >> 5;

  const __bf16* ga = xb + (size_t)(rowb * NT) * 16384;
  const __bf16* gb = wb + (size_t)(cb * NT) * 16384;

  // half h: mat = h&1 (0=A,1=B), kh = h>>1. one half = 2 block-wide gl16.
  auto stage_half = [&](int buf, int kt2, int h) {
    const int kh = h >> 1;
    const __bf16* gsrc = ((h & 1) ? gb : ga) + (size_t)kt2 * 16384 + kh * 8192;
    __bf16* lbase = ((h & 1) ? &Bs[buf][0] : &As[buf][0]) + kh * 8192;
    #pragma unroll
    for (int c = 0; c < 2; ++c)
      gl16(gsrc + c * 4096 + wv * 512 + lane * 8,
           lbase + c * 4096 + wv * 512);
  };

  // prologue: all 4 halves of kt=0 (8 loads); VM4 -> kh0 halves (h0,h1) done.
  // Steady invariant at P1 entry: kh0(kt) complete, kh1(kt) outstanding (4).
  #pragma unroll
  for (int h = 0; h < 4; ++h) stage_half(0, 0, h);
  VM4
  __builtin_amdgcn_s_barrier();

  f32x16 acc[4][2] = {};
  bf16x8 aF[2][2], bF[2][2];

  int cur = 0, kt = 0;
  const __bf16* A;
  const __bf16* B;
  bool do_stage = true;
  int nbuf;

  for (kt = 0; kt < NT - 1; ++kt) {
    A = &As[cur][0]; B = &Bs[cur][0]; nbuf = cur ^ 1;
    // P2's VM4 waits kh1(kt) [oldest 4 of 8]; P4's VM4 waits kh0(kt+1).
    PHASE(0, 0, 1, 0, NOVM)
    PHASE(1, 0, 0, 1, VM4)
    PHASE(0, 1, 1, 2, NOVM)
    PHASE(1, 1, 0, 3, VM4)
    cur ^= 1;
  }
  // peeled last K-tile: entry outstanding = kh1(kt_last) only -> VM0 drains.
  A = &As[cur][0]; B = &Bs[cur][0]; nbuf = cur ^ 1; do_stage = false;
  PHASE(0, 0, 1, 0, NOVM)
  PHASE(1, 0, 0, 1, VM0)
  PHASE(0, 1, 1, 2, NOVM)
  PHASE(1, 1, 0, 3, NOVM)

  __syncthreads();  // full fence before LDS reuse for the reduction

  // Epilogue: rows span 4 waves (wc 0..3) -> two-level reduce via LDS.
  // C/D layout: col = lane&31, row = (reg&3) + 8*(reg>>2) + 4*(lane>>5)
  float* redM = (float*)&As[0][0];   // [wc4][row256]
  float* redS = redM + 1024;
  #pragma unroll
  for (int mr = 0; mr < 4; ++mr) {
    #pragma unroll
    for (int reg = 0; reg < 16; ++reg) {
      const int rl = wr * 128 + mr * 32 + (reg & 3) + 8 * (reg >> 2) + 4 * hi;
      const float v0 = acc[mr][0][reg], v1 = acc[mr][1][reg];
      float mx = fmaxf(v0, v1);
      #pragma unroll
      for (int m = 1; m < 32; m <<= 1) mx = fmaxf(mx, __shfl_xor(mx, m, 64));
      float sv = expf(v0 - mx) + expf(v1 - mx);
      #pragma unroll
      for (int m = 1; m < 32; m <<= 1) sv += __shfl_xor(sv, m, 64);
      if (rlo == 0) { redM[wc * 256 + rl] = mx; redS[wc * 256 + rl] = sv; }
    }
  }
  __syncthreads();
  if (t < 256) {
    const float m0 = redM[t], m1 = redM[256 + t], m2 = redM[512 + t], m3 = redM[768 + t];
    float M = fmaxf(fmaxf(m0, m1), fmaxf(m2, m3));
    float S = redS[t] * expf(m0 - M) + redS[256 + t] * expf(m1 - M)
            + redS[512 + t] * expf(m2 - M) + redS[768 + t] * expf(m3 - M);
    const int grow = row0 + t;
    ws_m[(size_t)grow * NCB + cb] = M;
    ws_s[(size_t)grow * NCB + cb] = S;
  }
}

// ---- fallback: reg-staged 128^2 kernel (used if ws too small) ----
__global__ __launch_bounds__(256, 2)
void k_gemm_lse(const float* __restrict__ x, const float* __restrict__ w,
                const int* __restrict__ tgt,
                float* __restrict__ ws_m, float* __restrict__ ws_s,
                float* __restrict__ ws_t,
                int H, int NCB, int ROWB)
{
  __shared__ unsigned short As[2][BM * LDK];
  __shared__ unsigned short Bs[2][BN * LDK];

  const int bid  = blockIdx.x;
  const int rowb = bid % ROWB;
  const int cb   = bid / ROWB;
  const int row0 = rowb * BM;
  const int col0 = cb * BN;

  const int t    = threadIdx.x;
  const int lane = t & 63;
  const int wv   = t >> 6;
  const int sr = t >> 1;
  const int sk = (t & 1) * 16;

  const float* xa = x + (size_t)(row0 + sr) * H + sk;
  const float* wb = w + (size_t)(col0 + sr) * H + sk;

  float4 ra[4], rb[4];
  #pragma unroll
  for (int i = 0; i < 4; ++i) {
    ra[i] = *(const float4*)(xa + i * 4);
    rb[i] = *(const float4*)(wb + i * 4);
  }

  auto stage = [&](int buf) {
    uint4 p0, p1;
    p0.x = pkbf(ra[0].x, ra[0].y); p0.y = pkbf(ra[0].z, ra[0].w);
    p0.z = pkbf(ra[1].x, ra[1].y); p0.w = pkbf(ra[1].z, ra[1].w);
    p1.x = pkbf(ra[2].x, ra[2].y); p1.y = pkbf(ra[2].z, ra[2].w);
    p1.z = pkbf(ra[3].x, ra[3].y); p1.w = pkbf(ra[3].z, ra[3].w);
    *(uint4*)&As[buf][sr * LDK + sk]     = p0;
    *(uint4*)&As[buf][sr * LDK + sk + 8] = p1;
    p0.x = pkbf(rb[0].x, rb[0].y); p0.y = pkbf(rb[0].z, rb[0].w);
    p0.z = pkbf(rb[1].x, rb[1].y); p0.w = pkbf(rb[1].z, rb[1].w);
    p1.x = pkbf(rb[2].x, rb[2].y); p1.y = pkbf(rb[2].z, rb[2].w);
    p1.z = pkbf(rb[3].x, rb[3].y); p1.w = pkbf(rb[3].z, rb[3].w);
    *(uint4*)&Bs[buf][sr * LDK + sk]     = p0;
    *(uint4*)&Bs[buf][sr * LDK + sk + 8] = p1;
  };

  stage(0);
  __syncthreads();

  f32x16 acc[4] = {};
  const int rlo = lane & 31;
  const int hi  = lane >> 5;
  const int NT  = H / BK;
  int cur = 0;

  for (int kt = 0; kt < NT; ++kt) {
    const bool pf = (kt + 1 < NT);
    if (pf) {
      xa += BK; wb += BK;
      #pragma unroll
      for (int i = 0; i < 4; ++i) {
        ra[i] = *(const float4*)(xa + i * 4);
        rb[i] = *(const float4*)(wb + i * 4);
      }
    }
    const unsigned short* A = As[cur];
    const unsigned short* B = Bs[cur];
    #pragma unroll
    for (int ks = 0; ks < 2; ++ks) {
      const int koff = ks * 16 + hi * 8;
      bf16x8 a = *(const bf16x8*)&A[(wv * 32 + rlo) * LDK + koff];
      #pragma unroll
      for (int nf = 0; nf < 4; ++nf) {
        bf16x8 b = *(const bf16x8*)&B[(nf * 32 + rlo) * LDK + koff];
        acc[nf] = __builtin_amdgcn_mfma_f32_32x32x16_bf16(a, b, acc[nf], 0, 0, 0);
      }
    }
    if (pf) stage(cur ^ 1);
    __syncthreads();
    cur ^= 1;
  }

  #pragma unroll
  for (int reg = 0; reg < 16; ++reg) {
    const int row = wv * 32 + (reg & 3) + 8 * (reg >> 2) + 4 * hi;
    float mx = fmaxf(fmaxf(acc[0][reg], acc[1][reg]), fmaxf(acc[2][reg], acc[3][reg]));
    #pragma unroll
    for (int m = 1; m < 32; m <<= 1) mx = fmaxf(mx, __shfl_xor(mx, m, 64));
    float s = 0.f;
    #pragma unroll
    for (int nf = 0; nf < 4; ++nf) s += expf(acc[nf][reg] - mx);
    #pragma unroll
    for (int m = 1; m < 32; m <<= 1) s += __shfl_xor(s, m, 64);
    const int grow = row0 + row;
    if (rlo == 0) {
      ws_m[(size_t)grow * NCB + cb] = mx;
      ws_s[(size_t)grow * NCB + cb] = s;
    }
    const int tv = tgt[grow];
    #pragma unroll
    for (int nf = 0; nf < 4; ++nf) {
      if (tv == col0 + nf * 32 + rlo) ws_t[grow] = acc[nf][reg];
    }
  }
}

__global__ void k_rowlse(const float* __restrict__ ws_m, const float* __restrict__ ws_s,
                         const float* __restrict__ ws_t, const int* __restrict__ tgt,
                         float* __restrict__ out, float* __restrict__ ws_nll, int NCB)
{
  const int row = blockIdx.x;
  const int t = threadIdx.x;
  const float* pm = ws_m + (size_t)row * NCB;
  const float* ps = ws_s + (size_t)row * NCB;
  __shared__ float red[8];

  float M = -3.0e38f;
  for (int j = t; j < NCB; j += 256) M = fmaxf(M, pm[j]);
  #pragma unroll
  for (int m = 1; m < 64; m <<= 1) M = fmaxf(M, __shfl_xor(M, m, 64));
  if ((t & 63) == 0) red[t >> 6] = M;
  __syncthreads();
  M = fmaxf(fmaxf(red[0], red[1]), fmaxf(red[2], red[3]));

  float S = 0.f;
  for (int j = t; j < NCB; j += 256) S += ps[j] * expf(pm[j] - M);
  #pragma unroll
  for (int m = 1; m < 64; m <<= 1) S += __shfl_xor(S, m, 64);
  if ((t & 63) == 0) red[4 + (t >> 6)] = S;
  __syncthreads();

  if (t == 0) {
    S = red[4] + red[5] + red[6] + red[7];
    const float lse = M + logf(S);
    out[1 + row] = lse;
    const int tv = tgt[row];
    ws_nll[row] = (tv != -100) ? (lse - ws_t[row]) : 0.f;
  }
}

__global__ void k_loss(const float* __restrict__ ws_nll, const int* __restrict__ tgt,
                       float* __restrict__ out, int BT)
{
  const int t = threadIdx.x;
  float s = 0.f, c = 0.f;
  for (int i = t; i < BT; i += 256) {
    s += ws_nll[i];
    c += (tgt[i] != -100) ? 1.f : 0.f;
  }
  __shared__ float rs[4], rc[4];
  #pragma unroll
  for (int m = 1; m < 64; m <<= 1) { s += __shfl_xor(s, m, 64); c += __shfl_xor(c, m, 64); }
  if ((t & 63) == 0) { rs[t >> 6] = s; rc[t >> 6] = c; }
  __syncthreads();
  if (t == 0) {
    s = rs[0] + rs[1] + rs[2] + rs[3];
    c = rc[0] + rc[1] + rc[2] + rc[3];
    out[0] = s / c;
  }
}

extern "C" void kernel_launch(void* const* d_in, const int* in_sizes, int n_in,
                              void* d_out, int out_size, void* d_ws, size_t ws_size,
                              hipStream_t stream)
{
  const float* x  = (const float*)d_in[0];
  const float* w  = (const float*)d_in[1];
  const int* tgt  = (const int*)d_in[2];
  float* out      = (float*)d_out;

  const int BT = in_sizes[2];
  const int H  = in_sizes[0] / BT;          // 2048
  const int V  = in_sizes[1] / H;           // 128000

  const int NT    = H / 64;                 // 32
  const int ROWB  = BT / 256;               // 8
  const int NCB   = V / 256;                // 500

  const size_t bf_elems   = (size_t)BT * H + (size_t)V * H;
  const size_t need_bytes = bf_elems * 2 + ((size_t)2 * BT * NCB + 2 * (size_t)BT) * 4;

  if (ws_size >= need_bytes && (BT % 256) == 0 && (V % 256) == 0 && (H % 64) == 0) {
    // ws = x_bf | w_bf | m | s | tgt_logit | nll
    __bf16* x_bf = (__bf16*)d_ws;
    __bf16* w_bf = x_bf + (size_t)BT * H;
    float* ws_m   = (float*)(w_bf + (size_t)V * H);
    float* ws_s   = ws_m + (size_t)BT * NCB;
    float* ws_t   = ws_s + (size_t)BT * NCB;
    float* ws_nll = ws_t + BT;

    k_cvt256<<<(V / 256) * NT, 256, 0, stream>>>(w, w_bf, H, NT);
    k_cvt256<<<(BT / 256) * NT, 256, 0, stream>>>(x, x_bf, H, NT);
    k_tgt<<<BT / 4, 256, 0, stream>>>(x, w, tgt, ws_t, H);
    k_gemm8<<<ROWB * NCB, 512, 0, stream>>>(x_bf, w_bf, ws_m, ws_s, NT, NCB, ROWB);
    k_rowlse<<<BT, 256, 0, stream>>>(ws_m, ws_s, ws_t, tgt, out, ws_nll, NCB);
    k_loss<<<1, 256, 0, stream>>>(ws_nll, tgt, out, BT);
  } else {
    const int ROWB1 = BT / BM;              // 16
    const int NCB1  = V / BN;               // 1000
    float* ws_m   = (float*)d_ws;
    float* ws_s   = ws_m + (size_t)BT * NCB1;
    float* ws_t   = ws_s + (size_t)BT * NCB1;
    float* ws_nll = ws_t + BT;

    k_gemm_lse<<<ROWB1 * NCB1, 256, 0, stream>>>(x, w, tgt, ws_m, ws_s, ws_t, H, NCB1, ROWB1);
    k_rowlse<<<BT, 256, 0, stream>>>(ws_m, ws_s, ws_t, tgt, out, ws_nll, NCB1);
    k_loss<<<1, 256, 0, stream>>>(ws_nll, tgt, out, BT);
  }
}

// Round 7
// 1376.758 us; speedup vs baseline: 1.2400x; 1.1741x over previous
//
#include <hip/hip_runtime.h>
#include <hip/hip_bf16.h>

// Fused linear + cross-entropy forward.
//   x: [BT, H] fp32, weight: [V, H] fp32, target: [BT] int32
//   out: [0] = loss (fp32), [1..BT] = lse (fp32)
//
// Fast path:
//   K0: fp32 -> bf16 pre-pass, tiled [tile256][kt][kh2][kc4][row256][8]
//   Kt: exact fp32 target-logit dot (one wave per row)
//   K1: 256x256 bf16 GEMM, 16x16x32 MFMA (matrix-pipe > LDS-pipe balance),
//       4-slot LDS ring with 3-slot-deep prefetch, counted vmcnt(8),
//       dual barrier + lgkm0 + setprio, XCD swizzle
//   K2: per-row reduce -> lse, nll;  K3: mean -> loss
// Fallback path (small ws): reg-staged 128^2 kernel.

typedef __bf16 bf16x8 __attribute__((ext_vector_type(8)));
typedef float f32x4  __attribute__((ext_vector_type(4)));
typedef float f32x16 __attribute__((ext_vector_type(16)));

#define BM 128
#define BN 128
#define BK 32
#define LDK 40      // fallback kernel LDS pad

__device__ __forceinline__ unsigned pkbf(float a, float b) {
  __hip_bfloat162 h = __float22bfloat162_rn(float2{a, b});
  unsigned r;
  __builtin_memcpy(&r, &h, 4);
  return r;
}

// global -> LDS direct copy, 16B per lane. LDS dest must be wave-uniform base.
__device__ __forceinline__ void gl16(const void* g, const void* l) {
  using GP = const unsigned __attribute__((address_space(1)))*;
  using LP = unsigned __attribute__((address_space(3)))*;
  __builtin_amdgcn_global_load_lds((GP)(unsigned long long)g,
                                   (LP)(unsigned)(unsigned long long)l, 16, 0, 0);
}

// ---- K0: convert + retile into the 256x64 K-tile image ----
// dst tile (t256, kt) at (t256*NT + kt)*16384 elems, layout [kh2][kc4][row256][8].
__global__ __launch_bounds__(256)
void k_cvt256(const float* __restrict__ src, __bf16* __restrict__ dst, int H, int NT)
{
  const int bid = blockIdx.x;
  const int kt = bid % NT;
  const int r = threadIdx.x;
  const float* s = src + (size_t)((bid / NT) * 256 + r) * H + kt * 64;
  __bf16* d = dst + (size_t)bid * 16384;
  #pragma unroll
  for (int j = 0; j < 8; ++j) {
    float4 f0 = ((const float4*)s)[2 * j];
    float4 f1 = ((const float4*)s)[2 * j + 1];
    uint4 p;
    p.x = pkbf(f0.x, f0.y); p.y = pkbf(f0.z, f0.w);
    p.z = pkbf(f1.x, f1.y); p.w = pkbf(f1.z, f1.w);
    *(uint4*)(d + (j >> 2) * 8192 + (j & 3) * 2048 + r * 8) = p;
  }
}

// ---- Kt: exact fp32 target logit, one wave per row ----
__global__ __launch_bounds__(256)
void k_tgt(const float* __restrict__ x, const float* __restrict__ w,
           const int* __restrict__ tgt, float* __restrict__ ws_t, int H)
{
  const int row  = blockIdx.x * 4 + (threadIdx.x >> 6);
  const int lane = threadIdx.x & 63;
  const int tv = tgt[row];
  if (tv == -100) { if (lane == 0) ws_t[row] = 0.f; return; }
  const float* xr = x + (size_t)row * H;
  const float* wr = w + (size_t)tv * H;
  float acc = 0.f;
  for (int j = lane * 4; j < H; j += 256) {
    float4 a = *(const float4*)(xr + j);
    float4 b = *(const float4*)(wr + j);
    acc += a.x * b.x + a.y * b.y + a.z * b.z + a.w * b.w;
  }
  #pragma unroll
  for (int m = 1; m < 64; m <<= 1) acc += __shfl_xor(acc, m, 64);
  if (lane == 0) ws_t[row] = acc;
}

// ---- K1: 256^2 GEMM, 16x16x32 MFMA, 4-slot ring ----
#define VM8 asm volatile("s_waitcnt vmcnt(8)" ::: "memory");
#define VM4 asm volatile("s_waitcnt vmcnt(4)" ::: "memory");
#define VM0 asm volatile("s_waitcnt vmcnt(0)" ::: "memory");
#define NOVM

// One kh-slot (k-depth 32) = 2 phases x 16 MFMA. SL is the static ring slot,
// DO_ST/ST_S control prefetch of slot ST_S (3 ahead), WAITM ensures slot j+1
// complete before the trailing barrier.
#define SLOT(SL, DO_ST, ST_S, WAITM)                                            \
  {                                                                             \
    const __bf16* Ab = &As[SL][0];                                              \
    const __bf16* Bb = &Bs[SL][0];                                              \
    _Pragma("unroll")                                                           \
    for (int m = 0; m < 4; ++m)                                                 \
      aF[m] = *(const bf16x8*)&Ab[kcoff + (arow + m * 16) * 8];                 \
    _Pragma("unroll")                                                           \
    for (int n = 0; n < 4; ++n)                                                 \
      bF[n] = *(const bf16x8*)&Bb[kcoff + (bcol + n * 16) * 8];                 \
    if (DO_ST) stage_slot(ST_S);                                                \
    __builtin_amdgcn_s_barrier();                                               \
    asm volatile("s_waitcnt lgkmcnt(0)" ::: "memory");                          \
    __builtin_amdgcn_s_setprio(1);                                              \
    _Pragma("unroll")                                                           \
    for (int m = 0; m < 4; ++m)                                                 \
      _Pragma("unroll")                                                         \
      for (int n = 0; n < 4; ++n)                                               \
        acc[m][n] = __builtin_amdgcn_mfma_f32_16x16x32_bf16(aF[m], bF[n],       \
                                                            acc[m][n], 0, 0, 0);\
    __builtin_amdgcn_s_setprio(0);                                              \
    __builtin_amdgcn_s_barrier();                                               \
    _Pragma("unroll")                                                           \
    for (int m = 0; m < 4; ++m)                                                 \
      aF[m] = *(const bf16x8*)&Ab[kcoff + (arow + (m + 4) * 16) * 8];           \
    __builtin_amdgcn_s_barrier();                                               \
    asm volatile("s_waitcnt lgkmcnt(0)" ::: "memory");                          \
    __builtin_amdgcn_s_setprio(1);                                              \
    _Pragma("unroll")                                                           \
    for (int m = 0; m < 4; ++m)                                                 \
      _Pragma("unroll")                                                         \
      for (int n = 0; n < 4; ++n)                                               \
        acc[m + 4][n] = __builtin_amdgcn_mfma_f32_16x16x32_bf16(aF[m], bF[n],   \
                                                         acc[m + 4][n], 0, 0, 0);\
    __builtin_amdgcn_s_setprio(0);                                              \
    WAITM                                                                       \
    __builtin_amdgcn_s_barrier();                                               \
  }

__global__ __launch_bounds__(512, 2)
void k_gemm16(const __bf16* __restrict__ xb, const __bf16* __restrict__ wb,
              float* __restrict__ ws_m, float* __restrict__ ws_s,
              int NT, int NCB, int ROWB)
{
  __shared__ __bf16 As[4][8192];   // 4 kh-slots x 16KB (A)
  __shared__ __bf16 Bs[4][8192];   // 4 kh-slots x 16KB (B)

  // XCD swizzle: the 8 row-siblings of a column strip land on one XCD ->
  // B panel served from that XCD's L2.
  int wg = blockIdx.x;
  const int nwg = gridDim.x;
  if ((nwg & 7) == 0) wg = (wg & 7) * (nwg >> 3) + (wg >> 3);
  const int rowb = wg % ROWB;
  const int cb   = wg / ROWB;
  const int row0 = rowb * 256;

  const int t    = threadIdx.x;
  const int lane = t & 63;
  const int wv   = t >> 6;       // 8 waves: wr = wv>>2 (2), wc = wv&3 (4)
  const int wr   = wv >> 2;
  const int wc   = wv & 3;

  // 16x16x32 fragment addressing: lane covers row/col (lane&15) at k-chunk
  // (lane>>4)*8 within the kh-slot image [kc4][row256][8].
  const int kcoff = (lane >> 4) * 2048;
  const int arow  = wr * 128 + (lane & 15);
  const int bcol  = wc * 64 + (lane & 15);

  const __bf16* ga = xb + (size_t)(rowb * NT) * 16384;
  const __bf16* gb = wb + (size_t)(cb * NT) * 16384;

  // stage kh-slot s (A 16KB + B 16KB = 4 gl16 per thread) into ring slot s&3
  auto stage_slot = [&](int s) {
    const int ph = s & 3;
    const size_t off = (size_t)(s >> 1) * 16384 + (size_t)(s & 1) * 8192
                     + wv * 512 + lane * 8;
    const __bf16* a = ga + off;
    const __bf16* b = gb + off;
    gl16(a,        &As[ph][wv * 512]);
    gl16(a + 4096, &As[ph][4096 + wv * 512]);
    gl16(b,        &Bs[ph][wv * 512]);
    gl16(b + 4096, &Bs[ph][4096 + wv * 512]);
  };

  const int S = NT * 2;   // kh-slots total (S % 4 == 0, S >= 8)

  // prologue: 3 slots in flight (12 loads); VM8 -> slot 0 complete.
  stage_slot(0); stage_slot(1); stage_slot(2);
  VM8
  __builtin_amdgcn_s_barrier();

  f32x4 acc[8][4] = {};
  bf16x8 aF[4], bF[4];

  // main: slots j=0..S-5 in groups of 4 (static ring index). During slot j
  // stage slot j+3; end-of-slot VM8 leaves {j+2,j+3} (8 loads) outstanding,
  // guaranteeing j+1 complete (issued ~5 phases earlier).
  for (int g = 0; g < (S - 4) / 4; ++g) {
    const int j0 = g * 4;
    SLOT(0, true, j0 + 3, VM8)
    SLOT(1, true, j0 + 4, VM8)
    SLOT(2, true, j0 + 5, VM8)
    SLOT(3, true, j0 + 6, VM8)
  }
  // tail: j = S-4 (stage S-1), S-3, S-2, S-1
  SLOT(0, true,  S - 1, VM8)
  SLOT(1, false, 0,     VM4)
  SLOT(2, false, 0,     VM0)
  SLOT(3, false, 0,     NOVM)

  __syncthreads();  // full fence before LDS reuse for the reduction

  // Epilogue: per-row (128 cols of this block per wave-col-group) max/sumexp.
  // C/D 16x16 layout: col = lane&15, row = (lane>>4)*4 + reg.
  float* redM = (float*)&As[0][0];   // [wc4][row256]
  float* redS = redM + 1024;
  const int g4 = (lane >> 4) * 4;
  #pragma unroll
  for (int m = 0; m < 8; ++m) {
    #pragma unroll
    for (int r = 0; r < 4; ++r) {
      const int rl = wr * 128 + m * 16 + g4 + r;
      float mx = fmaxf(fmaxf(acc[m][0][r], acc[m][1][r]),
                       fmaxf(acc[m][2][r], acc[m][3][r]));
      #pragma unroll
      for (int sh = 1; sh < 16; sh <<= 1) mx = fmaxf(mx, __shfl_xor(mx, sh, 64));
      float sv = 0.f;
      #pragma unroll
      for (int n = 0; n < 4; ++n) sv += expf(acc[m][n][r] - mx);
      #pragma unroll
      for (int sh = 1; sh < 16; sh <<= 1) sv += __shfl_xor(sv, sh, 64);
      if ((lane & 15) == 0) { redM[wc * 256 + rl] = mx; redS[wc * 256 + rl] = sv; }
    }
  }
  __syncthreads();
  if (t < 256) {
    const float m0 = redM[t], m1 = redM[256 + t], m2 = redM[512 + t], m3 = redM[768 + t];
    float M = fmaxf(fmaxf(m0, m1), fmaxf(m2, m3));
    float S2 = redS[t] * expf(m0 - M) + redS[256 + t] * expf(m1 - M)
             + redS[512 + t] * expf(m2 - M) + redS[768 + t] * expf(m3 - M);
    const int grow = row0 + t;
    ws_m[(size_t)grow * NCB + cb] = M;
    ws_s[(size_t)grow * NCB + cb] = S2;
  }
}

// ---- fallback: reg-staged 128^2 kernel (used if ws too small) ----
__global__ __launch_bounds__(256, 2)
void k_gemm_lse(const float* __restrict__ x, const float* __restrict__ w,
                const int* __restrict__ tgt,
                float* __restrict__ ws_m, float* __restrict__ ws_s,
                float* __restrict__ ws_t,
                int H, int NCB, int ROWB)
{
  __shared__ unsigned short As[2][BM * LDK];
  __shared__ unsigned short Bs[2][BN * LDK];

  const int bid  = blockIdx.x;
  const int rowb = bid % ROWB;
  const int cb   = bid / ROWB;
  const int row0 = rowb * BM;
  const int col0 = cb * BN;

  const int t    = threadIdx.x;
  const int lane = t & 63;
  const int wv   = t >> 6;
  const int sr = t >> 1;
  const int sk = (t & 1) * 16;

  const float* xa = x + (size_t)(row0 + sr) * H + sk;
  const float* wb = w + (size_t)(col0 + sr) * H + sk;

  float4 ra[4], rb[4];
  #pragma unroll
  for (int i = 0; i < 4; ++i) {
    ra[i] = *(const float4*)(xa + i * 4);
    rb[i] = *(const float4*)(wb + i * 4);
  }

  auto stage = [&](int buf) {
    uint4 p0, p1;
    p0.x = pkbf(ra[0].x, ra[0].y); p0.y = pkbf(ra[0].z, ra[0].w);
    p0.z = pkbf(ra[1].x, ra[1].y); p0.w = pkbf(ra[1].z, ra[1].w);
    p1.x = pkbf(ra[2].x, ra[2].y); p1.y = pkbf(ra[2].z, ra[2].w);
    p1.z = pkbf(ra[3].x, ra[3].y); p1.w = pkbf(ra[3].z, ra[3].w);
    *(uint4*)&As[buf][sr * LDK + sk]     = p0;
    *(uint4*)&As[buf][sr * LDK + sk + 8] = p1;
    p0.x = pkbf(rb[0].x, rb[0].y); p0.y = pkbf(rb[0].z, rb[0].w);
    p0.z = pkbf(rb[1].x, rb[1].y); p0.w = pkbf(rb[1].z, rb[1].w);
    p1.x = pkbf(rb[2].x, rb[2].y); p1.y = pkbf(rb[2].z, rb[2].w);
    p1.z = pkbf(rb[3].x, rb[3].y); p1.w = pkbf(rb[3].z, rb[3].w);
    *(uint4*)&Bs[buf][sr * LDK + sk]     = p0;
    *(uint4*)&Bs[buf][sr * LDK + sk + 8] = p1;
  };

  stage(0);
  __syncthreads();

  f32x16 acc[4] = {};
  const int rlo = lane & 31;
  const int hi  = lane >> 5;
  const int NT  = H / BK;
  int cur = 0;

  for (int kt = 0; kt < NT; ++kt) {
    const bool pf = (kt + 1 < NT);
    if (pf) {
      xa += BK; wb += BK;
      #pragma unroll
      for (int i = 0; i < 4; ++i) {
        ra[i] = *(const float4*)(xa + i * 4);
        rb[i] = *(const float4*)(wb + i * 4);
      }
    }
    const unsigned short* A = As[cur];
    const unsigned short* B = Bs[cur];
    #pragma unroll
    for (int ks = 0; ks < 2; ++ks) {
      const int koff = ks * 16 + hi * 8;
      bf16x8 a = *(const bf16x8*)&A[(wv * 32 + rlo) * LDK + koff];
      #pragma unroll
      for (int nf = 0; nf < 4; ++nf) {
        bf16x8 b = *(const bf16x8*)&B[(nf * 32 + rlo) * LDK + koff];
        acc[nf] = __builtin_amdgcn_mfma_f32_32x32x16_bf16(a, b, acc[nf], 0, 0, 0);
      }
    }
    if (pf) stage(cur ^ 1);
    __syncthreads();
    cur ^= 1;
  }

  #pragma unroll
  for (int reg = 0; reg < 16; ++reg) {
    const int row = wv * 32 + (reg & 3) + 8 * (reg >> 2) + 4 * hi;
    float mx = fmaxf(fmaxf(acc[0][reg], acc[1][reg]), fmaxf(acc[2][reg], acc[3][reg]));
    #pragma unroll
    for (int m = 1; m < 32; m <<= 1) mx = fmaxf(mx, __shfl_xor(mx, m, 64));
    float s = 0.f;
    #pragma unroll
    for (int nf = 0; nf < 4; ++nf) s += expf(acc[nf][reg] - mx);
    #pragma unroll
    for (int m = 1; m < 32; m <<= 1) s += __shfl_xor(s, m, 64);
    const int grow = row0 + row;
    if (rlo == 0) {
      ws_m[(size_t)grow * NCB + cb] = mx;
      ws_s[(size_t)grow * NCB + cb] = s;
    }
    const int tv = tgt[grow];
    #pragma unroll
    for (int nf = 0; nf < 4; ++nf) {
      if (tv == col0 + nf * 32 + rlo) ws_t[grow] = acc[nf][reg];
    }
  }
}

__global__ void k_rowlse(const float* __restrict__ ws_m, const float* __restrict__ ws_s,
                         const float* __restrict__ ws_t, const int* __restrict__ tgt,
                         float* __restrict__ out, float* __restrict__ ws_nll, int NCB)
{
  const int row = blockIdx.x;
  const int t = threadIdx.x;
  const float* pm = ws_m + (size_t)row * NCB;
  const float* ps = ws_s + (size_t)row * NCB;
  __shared__ float red[8];

  float M = -3.0e38f;
  for (int j = t; j < NCB; j += 256) M = fmaxf(M, pm[j]);
  #pragma unroll
  for (int m = 1; m < 64; m <<= 1) M = fmaxf(M, __shfl_xor(M, m, 64));
  if ((t & 63) == 0) red[t >> 6] = M;
  __syncthreads();
  M = fmaxf(fmaxf(red[0], red[1]), fmaxf(red[2], red[3]));

  float S = 0.f;
  for (int j = t; j < NCB; j += 256) S += ps[j] * expf(pm[j] - M);
  #pragma unroll
  for (int m = 1; m < 64; m <<= 1) S += __shfl_xor(S, m, 64);
  if ((t & 63) == 0) red[4 + (t >> 6)] = S;
  __syncthreads();

  if (t == 0) {
    S = red[4] + red[5] + red[6] + red[7];
    const float lse = M + logf(S);
    out[1 + row] = lse;
    const int tv = tgt[row];
    ws_nll[row] = (tv != -100) ? (lse - ws_t[row]) : 0.f;
  }
}

__global__ void k_loss(const float* __restrict__ ws_nll, const int* __restrict__ tgt,
                       float* __restrict__ out, int BT)
{
  const int t = threadIdx.x;
  float s = 0.f, c = 0.f;
  for (int i = t; i < BT; i += 256) {
    s += ws_nll[i];
    c += (tgt[i] != -100) ? 1.f : 0.f;
  }
  __shared__ float rs[4], rc[4];
  #pragma unroll
  for (int m = 1; m < 64; m <<= 1) { s += __shfl_xor(s, m, 64); c += __shfl_xor(c, m, 64); }
  if ((t & 63) == 0) { rs[t >> 6] = s; rc[t >> 6] = c; }
  __syncthreads();
  if (t == 0) {
    s = rs[0] + rs[1] + rs[2] + rs[3];
    c = rc[0] + rc[1] + rc[2] + rc[3];
    out[0] = s / c;
  }
}

extern "C" void kernel_launch(void* const* d_in, const int* in_sizes, int n_in,
                              void* d_out, int out_size, void* d_ws, size_t ws_size,
                              hipStream_t stream)
{
  const float* x  = (const float*)d_in[0];
  const float* w  = (const float*)d_in[1];
  const int* tgt  = (const int*)d_in[2];
  float* out      = (float*)d_out;

  const int BT = in_sizes[2];
  const int H  = in_sizes[0] / BT;          // 2048
  const int V  = in_sizes[1] / H;           // 128000

  const int NT    = H / 64;                 // 32
  const int ROWB  = BT / 256;               // 8
  const int NCB   = V / 256;                // 500

  const size_t bf_elems   = (size_t)BT * H + (size_t)V * H;
  const size_t need_bytes = bf_elems * 2 + ((size_t)2 * BT * NCB + 2 * (size_t)BT) * 4;

  if (ws_size >= need_bytes && (BT % 256) == 0 && (V % 256) == 0 && (H % 128) == 0) {
    // ws = x_bf | w_bf | m | s | tgt_logit | nll
    __bf16* x_bf = (__bf16*)d_ws;
    __bf16* w_bf = x_bf + (size_t)BT * H;
    float* ws_m   = (float*)(w_bf + (size_t)V * H);
    float* ws_s   = ws_m + (size_t)BT * NCB;
    float* ws_t   = ws_s + (size_t)BT * NCB;
    float* ws_nll = ws_t + BT;

    k_cvt256<<<(V / 256) * NT, 256, 0, stream>>>(w, w_bf, H, NT);
    k_cvt256<<<(BT / 256) * NT, 256, 0, stream>>>(x, x_bf, H, NT);
    k_tgt<<<BT / 4, 256, 0, stream>>>(x, w, tgt, ws_t, H);
    k_gemm16<<<ROWB * NCB, 512, 0, stream>>>(x_bf, w_bf, ws_m, ws_s, NT, NCB, ROWB);
    k_rowlse<<<BT, 256, 0, stream>>>(ws_m, ws_s, ws_t, tgt, out, ws_nll, NCB);
    k_loss<<<1, 256, 0, stream>>>(ws_nll, tgt, out, BT);
  } else {
    const int ROWB1 = BT / BM;              // 16
    const int NCB1  = V / BN;               // 1000
    float* ws_m   = (float*)d_ws;
    float* ws_s   = ws_m + (size_t)BT * NCB1;
    float* ws_t   = ws_s + (size_t)BT * NCB1;
    float* ws_nll = ws_t + BT;

    k_gemm_lse<<<ROWB1 * NCB1, 256, 0, stream>>>(x, w, tgt, ws_m, ws_s, ws_t, H, NCB1, ROWB1);
    k_rowlse<<<BT, 256, 0, stream>>>(ws_m, ws_s, ws_t, tgt, out, ws_nll, NCB1);
    k_loss<<<1, 256, 0, stream>>>(ws_nll, tgt, out, BT);
  }
}

// Round 8
// 1315.412 us; speedup vs baseline: 1.2979x; 1.0466x over previous
//
#include <hip/hip_runtime.h>
#include <hip/hip_bf16.h>

// Fused linear + cross-entropy forward.
//   x: [BT, H] fp32, weight: [V, H] fp32, target: [BT] int32
//   out: [0] = loss (fp32), [1..BT] = lse (fp32)
//
// Fast path:
//   K0: fp32 -> bf16 pre-pass, tiled [tile256][kt][kh2][kc4][row256][8]
//   Kt: exact fp32 target-logit dot (one wave per row)
//   K1: 256x256 bf16 GEMM, 16x16x32 MFMA, 4-slot LDS ring (3 ahead, vmcnt(8)),
//       register-double-buffered fragments: NO lgkm drains, 2 barriers/slot
//   K2: per-row reduce -> lse, nll;  K3: mean -> loss
// Fallback path (small ws): reg-staged 128^2 kernel.

typedef __bf16 bf16x8 __attribute__((ext_vector_type(8)));
typedef float f32x4  __attribute__((ext_vector_type(4)));
typedef float f32x16 __attribute__((ext_vector_type(16)));

#define BM 128
#define BN 128
#define BK 32
#define LDK 40      // fallback kernel LDS pad

__device__ __forceinline__ unsigned pkbf(float a, float b) {
  __hip_bfloat162 h = __float22bfloat162_rn(float2{a, b});
  unsigned r;
  __builtin_memcpy(&r, &h, 4);
  return r;
}

// global -> LDS direct copy, 16B per lane. LDS dest must be wave-uniform base.
__device__ __forceinline__ void gl16(const void* g, const void* l) {
  using GP = const unsigned __attribute__((address_space(1)))*;
  using LP = unsigned __attribute__((address_space(3)))*;
  __builtin_amdgcn_global_load_lds((GP)(unsigned long long)g,
                                   (LP)(unsigned)(unsigned long long)l, 16, 0, 0);
}

// ---- K0: convert + retile into the 256x64 K-tile image ----
__global__ __launch_bounds__(256)
void k_cvt256(const float* __restrict__ src, __bf16* __restrict__ dst, int H, int NT)
{
  const int bid = blockIdx.x;
  const int kt = bid % NT;
  const int r = threadIdx.x;
  const float* s = src + (size_t)((bid / NT) * 256 + r) * H + kt * 64;
  __bf16* d = dst + (size_t)bid * 16384;
  #pragma unroll
  for (int j = 0; j < 8; ++j) {
    float4 f0 = ((const float4*)s)[2 * j];
    float4 f1 = ((const float4*)s)[2 * j + 1];
    uint4 p;
    p.x = pkbf(f0.x, f0.y); p.y = pkbf(f0.z, f0.w);
    p.z = pkbf(f1.x, f1.y); p.w = pkbf(f1.z, f1.w);
    *(uint4*)(d + (j >> 2) * 8192 + (j & 3) * 2048 + r * 8) = p;
  }
}

// ---- Kt: exact fp32 target logit, one wave per row ----
__global__ __launch_bounds__(256)
void k_tgt(const float* __restrict__ x, const float* __restrict__ w,
           const int* __restrict__ tgt, float* __restrict__ ws_t, int H)
{
  const int row  = blockIdx.x * 4 + (threadIdx.x >> 6);
  const int lane = threadIdx.x & 63;
  const int tv = tgt[row];
  if (tv == -100) { if (lane == 0) ws_t[row] = 0.f; return; }
  const float* xr = x + (size_t)row * H;
  const float* wr = w + (size_t)tv * H;
  float acc = 0.f;
  for (int j = lane * 4; j < H; j += 256) {
    float4 a = *(const float4*)(xr + j);
    float4 b = *(const float4*)(wr + j);
    acc += a.x * b.x + a.y * b.y + a.z * b.z + a.w * b.w;
  }
  #pragma unroll
  for (int m = 1; m < 64; m <<= 1) acc += __shfl_xor(acc, m, 64);
  if (lane == 0) ws_t[row] = acc;
}

// ---- K1: 256^2 GEMM, 16x16x32 MFMA, reg-dbuf fragments ----
#define VM8 asm volatile("s_waitcnt vmcnt(8)" ::: "memory");
#define VM4 asm volatile("s_waitcnt vmcnt(4)" ::: "memory");
#define VM0 asm volatile("s_waitcnt vmcnt(0)" ::: "memory");
#define NOVM
#define MEMFENCE asm volatile("" ::: "memory");

// One kh-slot j (ring SL, next ring SLN). Entering: a0 = sub0-frags of slot j,
// BCUR = B-frags of slot j (read during slot j-1). No lgkm drains anywhere:
// every MFMA's operands were ds_read >= one MFMA-cluster earlier.
//   TOP barrier: all waves' reads of ring slot (SL+... retiring) sampled
//                (forced by their MFMA sub1 lgkm) before stage overwrites it.
//   MID barrier (after counted VMW): all waves' stage of slot j+1 landed
//                before any wave's read-ahead of it.
#define SLOT(SL, SLN, BCUR, BNXT, DO_ST, ST_S, DO_RA, VMW)                      \
  {                                                                             \
    __builtin_amdgcn_s_barrier();                                               \
    MEMFENCE                                                                    \
    if (DO_ST) stage_slot(ST_S);                                                \
    _Pragma("unroll")                                                           \
    for (int m = 0; m < 4; ++m)                                                 \
      a1[m] = *(const bf16x8*)&As[SL][kcoff + (arow + (m + 4) * 16) * 8];       \
    __builtin_amdgcn_s_setprio(1);                                              \
    _Pragma("unroll")                                                           \
    for (int m = 0; m < 4; ++m)                                                 \
      _Pragma("unroll")                                                         \
      for (int n = 0; n < 4; ++n)                                               \
        acc[m][n] = __builtin_amdgcn_mfma_f32_16x16x32_bf16(a0[m], BCUR[n],     \
                                                            acc[m][n], 0, 0, 0);\
    __builtin_amdgcn_s_setprio(0);                                              \
    VMW                                                                         \
    __builtin_amdgcn_s_barrier();                                               \
    MEMFENCE                                                                    \
    if (DO_RA) {                                                                \
      _Pragma("unroll")                                                         \
      for (int m = 0; m < 4; ++m)                                               \
        a0[m] = *(const bf16x8*)&As[SLN][kcoff + (arow + m * 16) * 8];          \
      _Pragma("unroll")                                                         \
      for (int n = 0; n < 4; ++n)                                               \
        BNXT[n] = *(const bf16x8*)&Bs[SLN][kcoff + (bcol + n * 16) * 8];        \
    }                                                                           \
    __builtin_amdgcn_s_setprio(1);                                              \
    _Pragma("unroll")                                                           \
    for (int m = 0; m < 4; ++m)                                                 \
      _Pragma("unroll")                                                         \
      for (int n = 0; n < 4; ++n)                                               \
        acc[m + 4][n] = __builtin_amdgcn_mfma_f32_16x16x32_bf16(a1[m], BCUR[n], \
                                                         acc[m + 4][n], 0, 0, 0);\
    __builtin_amdgcn_s_setprio(0);                                              \
  }

__global__ __launch_bounds__(512, 2)
void k_gemm16(const __bf16* __restrict__ xb, const __bf16* __restrict__ wb,
              float* __restrict__ ws_m, float* __restrict__ ws_s,
              int NT, int NCB, int ROWB)
{
  __shared__ __bf16 As[4][8192];   // 4 kh-slots x 16KB (A)
  __shared__ __bf16 Bs[4][8192];   // 4 kh-slots x 16KB (B)

  // XCD swizzle
  int wg = blockIdx.x;
  const int nwg = gridDim.x;
  if ((nwg & 7) == 0) wg = (wg & 7) * (nwg >> 3) + (wg >> 3);
  const int rowb = wg % ROWB;
  const int cb   = wg / ROWB;
  const int row0 = rowb * 256;

  const int t    = threadIdx.x;
  const int lane = t & 63;
  const int wv   = t >> 6;       // 8 waves: wr = wv>>2 (2), wc = wv&3 (4)
  const int wr   = wv >> 2;
  const int wc   = wv & 3;

  // 16x16x32 fragment addressing within slot image [kc4][row256][8]
  const int kcoff = (lane >> 4) * 2048;
  const int arow  = wr * 128 + (lane & 15);
  const int bcol  = wc * 64 + (lane & 15);

  const __bf16* ga = xb + (size_t)(rowb * NT) * 16384;
  const __bf16* gb = wb + (size_t)(cb * NT) * 16384;

  auto stage_slot = [&](int s) {
    const int ph = s & 3;
    const size_t off = (size_t)(s >> 1) * 16384 + (size_t)(s & 1) * 8192
                     + wv * 512 + lane * 8;
    const __bf16* a = ga + off;
    const __bf16* b = gb + off;
    gl16(a,        &As[ph][wv * 512]);
    gl16(a + 4096, &As[ph][4096 + wv * 512]);
    gl16(b,        &Bs[ph][wv * 512]);
    gl16(b + 4096, &Bs[ph][4096 + wv * 512]);
  };

  const int S = NT * 2;   // kh-slots (S % 4 == 0, S >= 8)

  // prologue: 3 slots in flight (12 loads); VM8 -> slot 0 complete; barrier
  // makes it visible to all waves; then preload slot-0 sub0 + B frags.
  stage_slot(0); stage_slot(1); stage_slot(2);
  VM8
  __builtin_amdgcn_s_barrier();
  MEMFENCE

  f32x4 acc[8][4] = {};
  bf16x8 a0[4], a1[4], b0[4], b1[4];
  #pragma unroll
  for (int m = 0; m < 4; ++m)
    a0[m] = *(const bf16x8*)&As[0][kcoff + (arow + m * 16) * 8];
  #pragma unroll
  for (int n = 0; n < 4; ++n)
    b0[n] = *(const bf16x8*)&Bs[0][kcoff + (bcol + n * 16) * 8];

  // main: groups of 4 slots; slot j stages j+3, reads ahead slot j+1.
  // vmcnt at slot j: outstanding {j+1,j+2,j+3}=12 -> VM8 waits j+1 exactly.
  for (int g = 0; g < (S - 4) / 4; ++g) {
    const int j0 = g * 4;
    SLOT(0, 1, b0, b1, true, j0 + 3, true, VM8)
    SLOT(1, 2, b1, b0, true, j0 + 4, true, VM8)
    SLOT(2, 3, b0, b1, true, j0 + 5, true, VM8)
    SLOT(3, 0, b1, b0, true, j0 + 6, true, VM8)
  }
  // tail group: slots S-4..S-1. S-4 stages S-1; counts drain 12->8->4->0.
  SLOT(0, 1, b0, b1, true,  S - 1, true,  VM8)
  SLOT(1, 2, b1, b0, false, 0,     true,  VM4)
  SLOT(2, 3, b0, b1, false, 0,     true,  VM0)
  SLOT(3, 0, b1, b0, false, 0,     false, NOVM)

  __syncthreads();  // full fence before LDS reuse for the reduction

  // Epilogue: rows span 4 waves (wc 0..3) -> two-level reduce via LDS.
  // C/D 16x16 layout: col = lane&15, row = (lane>>4)*4 + reg.
  float* redM = (float*)&As[0][0];   // [wc4][row256]
  float* redS = redM + 1024;
  const int g4 = (lane >> 4) * 4;
  #pragma unroll
  for (int m = 0; m < 8; ++m) {
    #pragma unroll
    for (int r = 0; r < 4; ++r) {
      const int rl = wr * 128 + m * 16 + g4 + r;
      float mx = fmaxf(fmaxf(acc[m][0][r], acc[m][1][r]),
                       fmaxf(acc[m][2][r], acc[m][3][r]));
      #pragma unroll
      for (int sh = 1; sh < 16; sh <<= 1) mx = fmaxf(mx, __shfl_xor(mx, sh, 64));
      float sv = 0.f;
      #pragma unroll
      for (int n = 0; n < 4; ++n) sv += expf(acc[m][n][r] - mx);
      #pragma unroll
      for (int sh = 1; sh < 16; sh <<= 1) sv += __shfl_xor(sv, sh, 64);
      if ((lane & 15) == 0) { redM[wc * 256 + rl] = mx; redS[wc * 256 + rl] = sv; }
    }
  }
  __syncthreads();
  if (t < 256) {
    const float m0 = redM[t], m1 = redM[256 + t], m2 = redM[512 + t], m3 = redM[768 + t];
    float M = fmaxf(fmaxf(m0, m1), fmaxf(m2, m3));
    float S2 = redS[t] * expf(m0 - M) + redS[256 + t] * expf(m1 - M)
             + redS[512 + t] * expf(m2 - M) + redS[768 + t] * expf(m3 - M);
    const int grow = row0 + t;
    ws_m[(size_t)grow * NCB + cb] = M;
    ws_s[(size_t)grow * NCB + cb] = S2;
  }
}

// ---- fallback: reg-staged 128^2 kernel (used if ws too small) ----
__global__ __launch_bounds__(256, 2)
void k_gemm_lse(const float* __restrict__ x, const float* __restrict__ w,
                const int* __restrict__ tgt,
                float* __restrict__ ws_m, float* __restrict__ ws_s,
                float* __restrict__ ws_t,
                int H, int NCB, int ROWB)
{
  __shared__ unsigned short As[2][BM * LDK];
  __shared__ unsigned short Bs[2][BN * LDK];

  const int bid  = blockIdx.x;
  const int rowb = bid % ROWB;
  const int cb   = bid / ROWB;
  const int row0 = rowb * BM;
  const int col0 = cb * BN;

  const int t    = threadIdx.x;
  const int lane = t & 63;
  const int wv   = t >> 6;
  const int sr = t >> 1;
  const int sk = (t & 1) * 16;

  const float* xa = x + (size_t)(row0 + sr) * H + sk;
  const float* wb = w + (size_t)(col0 + sr) * H + sk;

  float4 ra[4], rb[4];
  #pragma unroll
  for (int i = 0; i < 4; ++i) {
    ra[i] = *(const float4*)(xa + i * 4);
    rb[i] = *(const float4*)(wb + i * 4);
  }

  auto stage = [&](int buf) {
    uint4 p0, p1;
    p0.x = pkbf(ra[0].x, ra[0].y); p0.y = pkbf(ra[0].z, ra[0].w);
    p0.z = pkbf(ra[1].x, ra[1].y); p0.w = pkbf(ra[1].z, ra[1].w);
    p1.x = pkbf(ra[2].x, ra[2].y); p1.y = pkbf(ra[2].z, ra[2].w);
    p1.z = pkbf(ra[3].x, ra[3].y); p1.w = pkbf(ra[3].z, ra[3].w);
    *(uint4*)&As[buf][sr * LDK + sk]     = p0;
    *(uint4*)&As[buf][sr * LDK + sk + 8] = p1;
    p0.x = pkbf(rb[0].x, rb[0].y); p0.y = pkbf(rb[0].z, rb[0].w);
    p0.z = pkbf(rb[1].x, rb[1].y); p0.w = pkbf(rb[1].z, rb[1].w);
    p1.x = pkbf(rb[2].x, rb[2].y); p1.y = pkbf(rb[2].z, rb[2].w);
    p1.z = pkbf(rb[3].x, rb[3].y); p1.w = pkbf(rb[3].z, rb[3].w);
    *(uint4*)&Bs[buf][sr * LDK + sk]     = p0;
    *(uint4*)&Bs[buf][sr * LDK + sk + 8] = p1;
  };

  stage(0);
  __syncthreads();

  f32x16 acc[4] = {};
  const int rlo = lane & 31;
  const int hi  = lane >> 5;
  const int NT  = H / BK;
  int cur = 0;

  for (int kt = 0; kt < NT; ++kt) {
    const bool pf = (kt + 1 < NT);
    if (pf) {
      xa += BK; wb += BK;
      #pragma unroll
      for (int i = 0; i < 4; ++i) {
        ra[i] = *(const float4*)(xa + i * 4);
        rb[i] = *(const float4*)(wb + i * 4);
      }
    }
    const unsigned short* A = As[cur];
    const unsigned short* B = Bs[cur];
    #pragma unroll
    for (int ks = 0; ks < 2; ++ks) {
      const int koff = ks * 16 + hi * 8;
      bf16x8 a = *(const bf16x8*)&A[(wv * 32 + rlo) * LDK + koff];
      #pragma unroll
      for (int nf = 0; nf < 4; ++nf) {
        bf16x8 b = *(const bf16x8*)&B[(nf * 32 + rlo) * LDK + koff];
        acc[nf] = __builtin_amdgcn_mfma_f32_32x32x16_bf16(a, b, acc[nf], 0, 0, 0);
      }
    }
    if (pf) stage(cur ^ 1);
    __syncthreads();
    cur ^= 1;
  }

  #pragma unroll
  for (int reg = 0; reg < 16; ++reg) {
    const int row = wv * 32 + (reg & 3) + 8 * (reg >> 2) + 4 * hi;
    float mx = fmaxf(fmaxf(acc[0][reg], acc[1][reg]), fmaxf(acc[2][reg], acc[3][reg]));
    #pragma unroll
    for (int m = 1; m < 32; m <<= 1) mx = fmaxf(mx, __shfl_xor(mx, m, 64));
    float s = 0.f;
    #pragma unroll
    for (int nf = 0; nf < 4; ++nf) s += expf(acc[nf][reg] - mx);
    #pragma unroll
    for (int m = 1; m < 32; m <<= 1) s += __shfl_xor(s, m, 64);
    const int grow = row0 + row;
    if (rlo == 0) {
      ws_m[(size_t)grow * NCB + cb] = mx;
      ws_s[(size_t)grow * NCB + cb] = s;
    }
    const int tv = tgt[grow];
    #pragma unroll
    for (int nf = 0; nf < 4; ++nf) {
      if (tv == col0 + nf * 32 + rlo) ws_t[grow] = acc[nf][reg];
    }
  }
}

__global__ void k_rowlse(const float* __restrict__ ws_m, const float* __restrict__ ws_s,
                         const float* __restrict__ ws_t, const int* __restrict__ tgt,
                         float* __restrict__ out, float* __restrict__ ws_nll, int NCB)
{
  const int row = blockIdx.x;
  const int t = threadIdx.x;
  const float* pm = ws_m + (size_t)row * NCB;
  const float* ps = ws_s + (size_t)row * NCB;
  __shared__ float red[8];

  float M = -3.0e38f;
  for (int j = t; j < NCB; j += 256) M = fmaxf(M, pm[j]);
  #pragma unroll
  for (int m = 1; m < 64; m <<= 1) M = fmaxf(M, __shfl_xor(M, m, 64));
  if ((t & 63) == 0) red[t >> 6] = M;
  __syncthreads();
  M = fmaxf(fmaxf(red[0], red[1]), fmaxf(red[2], red[3]));

  float S = 0.f;
  for (int j = t; j < NCB; j += 256) S += ps[j] * expf(pm[j] - M);
  #pragma unroll
  for (int m = 1; m < 64; m <<= 1) S += __shfl_xor(S, m, 64);
  if ((t & 63) == 0) red[4 + (t >> 6)] = S;
  __syncthreads();

  if (t == 0) {
    S = red[4] + red[5] + red[6] + red[7];
    const float lse = M + logf(S);
    out[1 + row] = lse;
    const int tv = tgt[row];
    ws_nll[row] = (tv != -100) ? (lse - ws_t[row]) : 0.f;
  }
}

__global__ void k_loss(const float* __restrict__ ws_nll, const int* __restrict__ tgt,
                       float* __restrict__ out, int BT)
{
  const int t = threadIdx.x;
  float s = 0.f, c = 0.f;
  for (int i = t; i < BT; i += 256) {
    s += ws_nll[i];
    c += (tgt[i] != -100) ? 1.f : 0.f;
  }
  __shared__ float rs[4], rc[4];
  #pragma unroll
  for (int m = 1; m < 64; m <<= 1) { s += __shfl_xor(s, m, 64); c += __shfl_xor(c, m, 64); }
  if ((t & 63) == 0) { rs[t >> 6] = s; rc[t >> 6] = c; }
  __syncthreads();
  if (t == 0) {
    s = rs[0] + rs[1] + rs[2] + rs[3];
    c = rc[0] + rc[1] + rc[2] + rc[3];
    out[0] = s / c;
  }
}

extern "C" void kernel_launch(void* const* d_in, const int* in_sizes, int n_in,
                              void* d_out, int out_size, void* d_ws, size_t ws_size,
                              hipStream_t stream)
{
  const float* x  = (const float*)d_in[0];
  const float* w  = (const float*)d_in[1];
  const int* tgt  = (const int*)d_in[2];
  float* out      = (float*)d_out;

  const int BT = in_sizes[2];
  const int H  = in_sizes[0] / BT;          // 2048
  const int V  = in_sizes[1] / H;           // 128000

  const int NT    = H / 64;                 // 32
  const int ROWB  = BT / 256;               // 8
  const int NCB   = V / 256;                // 500

  const size_t bf_elems   = (size_t)BT * H + (size_t)V * H;
  const size_t need_bytes = bf_elems * 2 + ((size_t)2 * BT * NCB + 2 * (size_t)BT) * 4;

  if (ws_size >= need_bytes && (BT % 256) == 0 && (V % 256) == 0 && (H % 128) == 0) {
    // ws = x_bf | w_bf | m | s | tgt_logit | nll
    __bf16* x_bf = (__bf16*)d_ws;
    __bf16* w_bf = x_bf + (size_t)BT * H;
    float* ws_m   = (float*)(w_bf + (size_t)V * H);
    float* ws_s   = ws_m + (size_t)BT * NCB;
    float* ws_t   = ws_s + (size_t)BT * NCB;
    float* ws_nll = ws_t + BT;

    k_cvt256<<<(V / 256) * NT, 256, 0, stream>>>(w, w_bf, H, NT);
    k_cvt256<<<(BT / 256) * NT, 256, 0, stream>>>(x, x_bf, H, NT);
    k_tgt<<<BT / 4, 256, 0, stream>>>(x, w, tgt, ws_t, H);
    k_gemm16<<<ROWB * NCB, 512, 0, stream>>>(x_bf, w_bf, ws_m, ws_s, NT, NCB, ROWB);
    k_rowlse<<<BT, 256, 0, stream>>>(ws_m, ws_s, ws_t, tgt, out, ws_nll, NCB);
    k_loss<<<1, 256, 0, stream>>>(ws_nll, tgt, out, BT);
  } else {
    const int ROWB1 = BT / BM;              // 16
    const int NCB1  = V / BN;               // 1000
    float* ws_m   = (float*)d_ws;
    float* ws_s   = ws_m + (size_t)BT * NCB1;
    float* ws_t   = ws_s + (size_t)BT * NCB1;
    float* ws_nll = ws_t + BT;

    k_gemm_lse<<<ROWB1 * NCB1, 256, 0, stream>>>(x, w, tgt, ws_m, ws_s, ws_t, H, NCB1, ROWB1);
    k_rowlse<<<BT, 256, 0, stream>>>(ws_m, ws_s, ws_t, tgt, out, ws_nll, NCB1);
    k_loss<<<1, 256, 0, stream>>>(ws_nll, tgt, out, BT);
  }
}

// Round 9
// 1307.022 us; speedup vs baseline: 1.3062x; 1.0064x over previous
//
#include <hip/hip_runtime.h>
#include <hip/hip_bf16.h>

// Fused linear + cross-entropy forward.
//   x: [BT, H] fp32, weight: [V, H] fp32, target: [BT] int32
//   out: [0] = loss (fp32), [1..BT] = lse (fp32)
//
// Fast path:
//   K0: fp32 -> bf16 pre-pass, tiled [tile256][kt][kh2][kc4][row256][8]
//   Kt: exact fp32 target-logit dot (one wave per row)
//   K1: 256x256 bf16 GEMM, 16x16x32 MFMA, 4-slot LDS ring staged 2 ahead,
//       reg-dbuf fragments, ONE barrier per slot (WAR gap = 2 slots+2 barriers
//       +gl16 latency), counted vmcnt(4)
//   K2: per-row reduce -> lse, nll;  K3: mean -> loss
// Fallback path (small ws): reg-staged 128^2 kernel.

typedef __bf16 bf16x8 __attribute__((ext_vector_type(8)));
typedef float f32x4  __attribute__((ext_vector_type(4)));
typedef float f32x16 __attribute__((ext_vector_type(16)));

#define BM 128
#define BN 128
#define BK 32
#define LDK 40      // fallback kernel LDS pad

__device__ __forceinline__ unsigned pkbf(float a, float b) {
  __hip_bfloat162 h = __float22bfloat162_rn(float2{a, b});
  unsigned r;
  __builtin_memcpy(&r, &h, 4);
  return r;
}

// global -> LDS direct copy, 16B per lane. LDS dest must be wave-uniform base.
__device__ __forceinline__ void gl16(const void* g, const void* l) {
  using GP = const unsigned __attribute__((address_space(1)))*;
  using LP = unsigned __attribute__((address_space(3)))*;
  __builtin_amdgcn_global_load_lds((GP)(unsigned long long)g,
                                   (LP)(unsigned)(unsigned long long)l, 16, 0, 0);
}

// ---- K0: convert + retile into the 256x64 K-tile image ----
__global__ __launch_bounds__(256)
void k_cvt256(const float* __restrict__ src, __bf16* __restrict__ dst, int H, int NT)
{
  const int bid = blockIdx.x;
  const int kt = bid % NT;
  const int r = threadIdx.x;
  const float* s = src + (size_t)((bid / NT) * 256 + r) * H + kt * 64;
  __bf16* d = dst + (size_t)bid * 16384;
  #pragma unroll
  for (int j = 0; j < 8; ++j) {
    float4 f0 = ((const float4*)s)[2 * j];
    float4 f1 = ((const float4*)s)[2 * j + 1];
    uint4 p;
    p.x = pkbf(f0.x, f0.y); p.y = pkbf(f0.z, f0.w);
    p.z = pkbf(f1.x, f1.y); p.w = pkbf(f1.z, f1.w);
    *(uint4*)(d + (j >> 2) * 8192 + (j & 3) * 2048 + r * 8) = p;
  }
}

// ---- Kt: exact fp32 target logit, one wave per row ----
__global__ __launch_bounds__(256)
void k_tgt(const float* __restrict__ x, const float* __restrict__ w,
           const int* __restrict__ tgt, float* __restrict__ ws_t, int H)
{
  const int row  = blockIdx.x * 4 + (threadIdx.x >> 6);
  const int lane = threadIdx.x & 63;
  const int tv = tgt[row];
  if (tv == -100) { if (lane == 0) ws_t[row] = 0.f; return; }
  const float* xr = x + (size_t)row * H;
  const float* wr = w + (size_t)tv * H;
  float acc = 0.f;
  for (int j = lane * 4; j < H; j += 256) {
    float4 a = *(const float4*)(xr + j);
    float4 b = *(const float4*)(wr + j);
    acc += a.x * b.x + a.y * b.y + a.z * b.z + a.w * b.w;
  }
  #pragma unroll
  for (int m = 1; m < 64; m <<= 1) acc += __shfl_xor(acc, m, 64);
  if (lane == 0) ws_t[row] = acc;
}

// ---- K1: 256^2 GEMM, 16x16x32 MFMA, 1 barrier/slot ----
#define VM4 asm volatile("s_waitcnt vmcnt(4)" ::: "memory");
#define VM0 asm volatile("s_waitcnt vmcnt(0)" ::: "memory");
#define NOVM
#define MEMFENCE asm volatile("" ::: "memory");

// One kh-slot j (ring SL, next ring SLN). Entering: a0/BCUR = frags of slot j
// (read during slot j-1 after its barrier). Order:
//   read a1(j) -> MFMA sub0 (a0 x BCUR) -> stage(j+2) -> VM4 -> BARRIER ->
//   read-ahead a0/BNXT of slot j+1 -> MFMA sub1 (a1 x BCUR)
// Hazards: RAW (stage j+1 done before read-ahead) = VM4 counts {j+1,j+2}=8->4
//   + barrier.  WAR (stage(j+2) overwrites slot j-2's ring): last reads of
//   that data were lgkm-forced before barrier(j-1); stage issues after it,
//   and its LDS write lands ~500cy later still.  No lgkm drains: every MFMA
//   operand was ds_read >= one 16-MFMA cluster (~310cy) earlier.
#define SLOT(SL, SLN, BCUR, BNXT, DO_ST, ST_S, DO_RA, VMW, DO_BAR)              \
  {                                                                             \
    _Pragma("unroll")                                                           \
    for (int m = 0; m < 4; ++m)                                                 \
      a1[m] = *(const bf16x8*)&As[SL][kcoff + (arow + (m + 4) * 16) * 8];       \
    __builtin_amdgcn_s_setprio(1);                                              \
    _Pragma("unroll")                                                           \
    for (int m = 0; m < 4; ++m)                                                 \
      _Pragma("unroll")                                                         \
      for (int n = 0; n < 4; ++n)                                               \
        acc[m][n] = __builtin_amdgcn_mfma_f32_16x16x32_bf16(a0[m], BCUR[n],     \
                                                            acc[m][n], 0, 0, 0);\
    __builtin_amdgcn_s_setprio(0);                                              \
    if (DO_ST) stage_slot(ST_S);                                                \
    VMW                                                                         \
    if (DO_BAR) { __builtin_amdgcn_s_barrier(); MEMFENCE }                      \
    if (DO_RA) {                                                                \
      _Pragma("unroll")                                                         \
      for (int m = 0; m < 4; ++m)                                               \
        a0[m] = *(const bf16x8*)&As[SLN][kcoff + (arow + m * 16) * 8];          \
      _Pragma("unroll")                                                         \
      for (int n = 0; n < 4; ++n)                                               \
        BNXT[n] = *(const bf16x8*)&Bs[SLN][kcoff + (bcol + n * 16) * 8];        \
    }                                                                           \
    __builtin_amdgcn_s_setprio(1);                                              \
    _Pragma("unroll")                                                           \
    for (int m = 0; m < 4; ++m)                                                 \
      _Pragma("unroll")                                                         \
      for (int n = 0; n < 4; ++n)                                               \
        acc[m + 4][n] = __builtin_amdgcn_mfma_f32_16x16x32_bf16(a1[m], BCUR[n], \
                                                         acc[m + 4][n], 0, 0, 0);\
    __builtin_amdgcn_s_setprio(0);                                              \
  }

__global__ __launch_bounds__(512, 2)
void k_gemm16(const __bf16* __restrict__ xb, const __bf16* __restrict__ wb,
              float* __restrict__ ws_m, float* __restrict__ ws_s,
              int NT, int NCB, int ROWB)
{
  __shared__ __bf16 As[4][8192];   // 4 kh-slots x 16KB (A)
  __shared__ __bf16 Bs[4][8192];   // 4 kh-slots x 16KB (B)

  // XCD swizzle
  int wg = blockIdx.x;
  const int nwg = gridDim.x;
  if ((nwg & 7) == 0) wg = (wg & 7) * (nwg >> 3) + (wg >> 3);
  const int rowb = wg % ROWB;
  const int cb   = wg / ROWB;
  const int row0 = rowb * 256;

  const int t    = threadIdx.x;
  const int lane = t & 63;
  const int wv   = t >> 6;       // 8 waves: wr = wv>>2 (2), wc = wv&3 (4)
  const int wr   = wv >> 2;
  const int wc   = wv & 3;

  // 16x16x32 fragment addressing within slot image [kc4][row256][8]
  const int kcoff = (lane >> 4) * 2048;
  const int arow  = wr * 128 + (lane & 15);
  const int bcol  = wc * 64 + (lane & 15);

  const __bf16* ga = xb + (size_t)(rowb * NT) * 16384;
  const __bf16* gb = wb + (size_t)(cb * NT) * 16384;

  auto stage_slot = [&](int s) {
    const int ph = s & 3;
    const size_t off = (size_t)(s >> 1) * 16384 + (size_t)(s & 1) * 8192
                     + wv * 512 + lane * 8;
    const __bf16* a = ga + off;
    const __bf16* b = gb + off;
    gl16(a,        &As[ph][wv * 512]);
    gl16(a + 4096, &As[ph][4096 + wv * 512]);
    gl16(b,        &Bs[ph][wv * 512]);
    gl16(b + 4096, &Bs[ph][4096 + wv * 512]);
  };

  const int S = NT * 2;   // kh-slots (S % 4 == 0, S >= 8)

  // prologue: 2 slots in flight (8 loads); VM4 -> slot 0 complete; barrier;
  // preload slot-0 sub0 + B frags.
  stage_slot(0); stage_slot(1);
  VM4
  __builtin_amdgcn_s_barrier();
  MEMFENCE

  f32x4 acc[8][4] = {};
  bf16x8 a0[4], a1[4], b0[4], b1[4];
  #pragma unroll
  for (int m = 0; m < 4; ++m)
    a0[m] = *(const bf16x8*)&As[0][kcoff + (arow + m * 16) * 8];
  #pragma unroll
  for (int n = 0; n < 4; ++n)
    b0[n] = *(const bf16x8*)&Bs[0][kcoff + (bcol + n * 16) * 8];

  // main: groups of 4 slots; slot j stages j+2, reads ahead slot j+1.
  // VM4 at slot j: outstanding {j+1,j+2}=8 -> waits j+1 exactly.
  for (int g = 0; g < (S - 4) / 4; ++g) {
    const int j0 = g * 4;
    SLOT(0, 1, b0, b1, true, j0 + 2, true, VM4, true)
    SLOT(1, 2, b1, b0, true, j0 + 3, true, VM4, true)
    SLOT(2, 3, b0, b1, true, j0 + 4, true, VM4, true)
    SLOT(3, 0, b1, b0, true, j0 + 5, true, VM4, true)
  }
  // tail: slots S-4..S-1. S-4 stages S-2, S-3 stages S-1; counts 8->4->0.
  SLOT(0, 1, b0, b1, true,  S - 2, true,  VM4, true)
  SLOT(1, 2, b1, b0, true,  S - 1, true,  VM4, true)
  SLOT(2, 3, b0, b1, false, 0,     true,  VM0, true)
  SLOT(3, 0, b1, b0, false, 0,     false, NOVM, false)

  __syncthreads();  // full fence before LDS reuse for the reduction

  // Epilogue: rows span 4 waves (wc 0..3) -> two-level reduce via LDS.
  // C/D 16x16 layout: col = lane&15, row = (lane>>4)*4 + reg.
  float* redM = (float*)&As[0][0];   // [wc4][row256]
  float* redS = redM + 1024;
  const int g4 = (lane >> 4) * 4;
  #pragma unroll
  for (int m = 0; m < 8; ++m) {
    #pragma unroll
    for (int r = 0; r < 4; ++r) {
      const int rl = wr * 128 + m * 16 + g4 + r;
      float mx = fmaxf(fmaxf(acc[m][0][r], acc[m][1][r]),
                       fmaxf(acc[m][2][r], acc[m][3][r]));
      #pragma unroll
      for (int sh = 1; sh < 16; sh <<= 1) mx = fmaxf(mx, __shfl_xor(mx, sh, 64));
      float sv = 0.f;
      #pragma unroll
      for (int n = 0; n < 4; ++n) sv += expf(acc[m][n][r] - mx);
      #pragma unroll
      for (int sh = 1; sh < 16; sh <<= 1) sv += __shfl_xor(sv, sh, 64);
      if ((lane & 15) == 0) { redM[wc * 256 + rl] = mx; redS[wc * 256 + rl] = sv; }
    }
  }
  __syncthreads();
  if (t < 256) {
    const float m0 = redM[t], m1 = redM[256 + t], m2 = redM[512 + t], m3 = redM[768 + t];
    float M = fmaxf(fmaxf(m0, m1), fmaxf(m2, m3));
    float S2 = redS[t] * expf(m0 - M) + redS[256 + t] * expf(m1 - M)
             + redS[512 + t] * expf(m2 - M) + redS[768 + t] * expf(m3 - M);
    const int grow = row0 + t;
    ws_m[(size_t)grow * NCB + cb] = M;
    ws_s[(size_t)grow * NCB + cb] = S2;
  }
}

// ---- fallback: reg-staged 128^2 kernel (used if ws too small) ----
__global__ __launch_bounds__(256, 2)
void k_gemm_lse(const float* __restrict__ x, const float* __restrict__ w,
                const int* __restrict__ tgt,
                float* __restrict__ ws_m, float* __restrict__ ws_s,
                float* __restrict__ ws_t,
                int H, int NCB, int ROWB)
{
  __shared__ unsigned short As[2][BM * LDK];
  __shared__ unsigned short Bs[2][BN * LDK];

  const int bid  = blockIdx.x;
  const int rowb = bid % ROWB;
  const int cb   = bid / ROWB;
  const int row0 = rowb * BM;
  const int col0 = cb * BN;

  const int t    = threadIdx.x;
  const int lane = t & 63;
  const int wv   = t >> 6;
  const int sr = t >> 1;
  const int sk = (t & 1) * 16;

  const float* xa = x + (size_t)(row0 + sr) * H + sk;
  const float* wb = w + (size_t)(col0 + sr) * H + sk;

  float4 ra[4], rb[4];
  #pragma unroll
  for (int i = 0; i < 4; ++i) {
    ra[i] = *(const float4*)(xa + i * 4);
    rb[i] = *(const float4*)(wb + i * 4);
  }

  auto stage = [&](int buf) {
    uint4 p0, p1;
    p0.x = pkbf(ra[0].x, ra[0].y); p0.y = pkbf(ra[0].z, ra[0].w);
    p0.z = pkbf(ra[1].x, ra[1].y); p0.w = pkbf(ra[1].z, ra[1].w);
    p1.x = pkbf(ra[2].x, ra[2].y); p1.y = pkbf(ra[2].z, ra[2].w);
    p1.z = pkbf(ra[3].x, ra[3].y); p1.w = pkbf(ra[3].z, ra[3].w);
    *(uint4*)&As[buf][sr * LDK + sk]     = p0;
    *(uint4*)&As[buf][sr * LDK + sk + 8] = p1;
    p0.x = pkbf(rb[0].x, rb[0].y); p0.y = pkbf(rb[0].z, rb[0].w);
    p0.z = pkbf(rb[1].x, rb[1].y); p0.w = pkbf(rb[1].z, rb[1].w);
    p1.x = pkbf(rb[2].x, rb[2].y); p1.y = pkbf(rb[2].z, rb[2].w);
    p1.z = pkbf(rb[3].x, rb[3].y); p1.w = pkbf(rb[3].z, rb[3].w);
    *(uint4*)&Bs[buf][sr * LDK + sk]     = p0;
    *(uint4*)&Bs[buf][sr * LDK + sk + 8] = p1;
  };

  stage(0);
  __syncthreads();

  f32x16 acc[4] = {};
  const int rlo = lane & 31;
  const int hi  = lane >> 5;
  const int NT  = H / BK;
  int cur = 0;

  for (int kt = 0; kt < NT; ++kt) {
    const bool pf = (kt + 1 < NT);
    if (pf) {
      xa += BK; wb += BK;
      #pragma unroll
      for (int i = 0; i < 4; ++i) {
        ra[i] = *(const float4*)(xa + i * 4);
        rb[i] = *(const float4*)(wb + i * 4);
      }
    }
    const unsigned short* A = As[cur];
    const unsigned short* B = Bs[cur];
    #pragma unroll
    for (int ks = 0; ks < 2; ++ks) {
      const int koff = ks * 16 + hi * 8;
      bf16x8 a = *(const bf16x8*)&A[(wv * 32 + rlo) * LDK + koff];
      #pragma unroll
      for (int nf = 0; nf < 4; ++nf) {
        bf16x8 b = *(const bf16x8*)&B[(nf * 32 + rlo) * LDK + koff];
        acc[nf] = __builtin_amdgcn_mfma_f32_32x32x16_bf16(a, b, acc[nf], 0, 0, 0);
      }
    }
    if (pf) stage(cur ^ 1);
    __syncthreads();
    cur ^= 1;
  }

  #pragma unroll
  for (int reg = 0; reg < 16; ++reg) {
    const int row = wv * 32 + (reg & 3) + 8 * (reg >> 2) + 4 * hi;
    float mx = fmaxf(fmaxf(acc[0][reg], acc[1][reg]), fmaxf(acc[2][reg], acc[3][reg]));
    #pragma unroll
    for (int m = 1; m < 32; m <<= 1) mx = fmaxf(mx, __shfl_xor(mx, m, 64));
    float s = 0.f;
    #pragma unroll
    for (int nf = 0; nf < 4; ++nf) s += expf(acc[nf][reg] - mx);
    #pragma unroll
    for (int m = 1; m < 32; m <<= 1) s += __shfl_xor(s, m, 64);
    const int grow = row0 + row;
    if (rlo == 0) {
      ws_m[(size_t)grow * NCB + cb] = mx;
      ws_s[(size_t)grow * NCB + cb] = s;
    }
    const int tv = tgt[grow];
    #pragma unroll
    for (int nf = 0; nf < 4; ++nf) {
      if (tv == col0 + nf * 32 + rlo) ws_t[grow] = acc[nf][reg];
    }
  }
}

__global__ void k_rowlse(const float* __restrict__ ws_m, const float* __restrict__ ws_s,
                         const float* __restrict__ ws_t, const int* __restrict__ tgt,
                         float* __restrict__ out, float* __restrict__ ws_nll, int NCB)
{
  const int row = blockIdx.x;
  const int t = threadIdx.x;
  const float* pm = ws_m + (size_t)row * NCB;
  const float* ps = ws_s + (size_t)row * NCB;
  __shared__ float red[8];

  float M = -3.0e38f;
  for (int j = t; j < NCB; j += 256) M = fmaxf(M, pm[j]);
  #pragma unroll
  for (int m = 1; m < 64; m <<= 1) M = fmaxf(M, __shfl_xor(M, m, 64));
  if ((t & 63) == 0) red[t >> 6] = M;
  __syncthreads();
  M = fmaxf(fmaxf(red[0], red[1]), fmaxf(red[2], red[3]));

  float S = 0.f;
  for (int j = t; j < NCB; j += 256) S += ps[j] * expf(pm[j] - M);
  #pragma unroll
  for (int m = 1; m < 64; m <<= 1) S += __shfl_xor(S, m, 64);
  if ((t & 63) == 0) red[4 + (t >> 6)] = S;
  __syncthreads();

  if (t == 0) {
    S = red[4] + red[5] + red[6] + red[7];
    const float lse = M + logf(S);
    out[1 + row] = lse;
    const int tv = tgt[row];
    ws_nll[row] = (tv != -100) ? (lse - ws_t[row]) : 0.f;
  }
}

__global__ void k_loss(const float* __restrict__ ws_nll, const int* __restrict__ tgt,
                       float* __restrict__ out, int BT)
{
  const int t = threadIdx.x;
  float s = 0.f, c = 0.f;
  for (int i = t; i < BT; i += 256) {
    s += ws_nll[i];
    c += (tgt[i] != -100) ? 1.f : 0.f;
  }
  __shared__ float rs[4], rc[4];
  #pragma unroll
  for (int m = 1; m < 64; m <<= 1) { s += __shfl_xor(s, m, 64); c += __shfl_xor(c, m, 64); }
  if ((t & 63) == 0) { rs[t >> 6] = s; rc[t >> 6] = c; }
  __syncthreads();
  if (t == 0) {
    s = rs[0] + rs[1] + rs[2] + rs[3];
    c = rc[0] + rc[1] + rc[2] + rc[3];
    out[0] = s / c;
  }
}

extern "C" void kernel_launch(void* const* d_in, const int* in_sizes, int n_in,
                              void* d_out, int out_size, void* d_ws, size_t ws_size,
                              hipStream_t stream)
{
  const float* x  = (const float*)d_in[0];
  const float* w  = (const float*)d_in[1];
  const int* tgt  = (const int*)d_in[2];
  float* out      = (float*)d_out;

  const int BT = in_sizes[2];
  const int H  = in_sizes[0] / BT;          // 2048
  const int V  = in_sizes[1] / H;           // 128000

  const int NT    = H / 64;                 // 32
  const int ROWB  = BT / 256;               // 8
  const int NCB   = V / 256;                // 500

  const size_t bf_elems   = (size_t)BT * H + (size_t)V * H;
  const size_t need_bytes = bf_elems * 2 + ((size_t)2 * BT * NCB + 2 * (size_t)BT) * 4;

  if (ws_size >= need_bytes && (BT % 256) == 0 && (V % 256) == 0 && (H % 128) == 0) {
    // ws = x_bf | w_bf | m | s | tgt_logit | nll
    __bf16* x_bf = (__bf16*)d_ws;
    __bf16* w_bf = x_bf + (size_t)BT * H;
    float* ws_m   = (float*)(w_bf + (size_t)V * H);
    float* ws_s   = ws_m + (size_t)BT * NCB;
    float* ws_t   = ws_s + (size_t)BT * NCB;
    float* ws_nll = ws_t + BT;

    k_cvt256<<<(V / 256) * NT, 256, 0, stream>>>(w, w_bf, H, NT);
    k_cvt256<<<(BT / 256) * NT, 256, 0, stream>>>(x, x_bf, H, NT);
    k_tgt<<<BT / 4, 256, 0, stream>>>(x, w, tgt, ws_t, H);
    k_gemm16<<<ROWB * NCB, 512, 0, stream>>>(x_bf, w_bf, ws_m, ws_s, NT, NCB, ROWB);
    k_rowlse<<<BT, 256, 0, stream>>>(ws_m, ws_s, ws_t, tgt, out, ws_nll, NCB);
    k_loss<<<1, 256, 0, stream>>>(ws_nll, tgt, out, BT);
  } else {
    const int ROWB1 = BT / BM;              // 16
    const int NCB1  = V / BN;               // 1000
    float* ws_m   = (float*)d_ws;
    float* ws_s   = ws_m + (size_t)BT * NCB1;
    float* ws_t   = ws_s + (size_t)BT * NCB1;
    float* ws_nll = ws_t + BT;

    k_gemm_lse<<<ROWB1 * NCB1, 256, 0, stream>>>(x, w, tgt, ws_m, ws_s, ws_t, H, NCB1, ROWB1);
    k_rowlse<<<BT, 256, 0, stream>>>(ws_m, ws_s, ws_t, tgt, out, ws_nll, NCB1);
    k_loss<<<1, 256, 0, stream>>>(ws_nll, tgt, out, BT);
  }
}